// Round 15
// baseline (159.701 us; speedup 1.0000x reference)
//
#include <hip/hip_runtime.h>

typedef unsigned short u16;
typedef __attribute__((ext_vector_type(8))) short short8;   // 8 bf16 = 4 VGPR
typedef __attribute__((ext_vector_type(4))) float f32x4;    // MFMA acc

// Problem constants
constexpr int B_  = 8;
constexpr int C_  = 512;
constexpr int T_  = 1024;   // H*W
constexpr int S_  = 1024;
constexpr int D_  = 512;
constexpr int NH_ = 8;
constexpr int BT_ = B_ * T_;   // 8192
constexpr float INVLN2 = 1.44269504088896340736f;
constexpr float QSCALE2 = 0.0125f * INVLN2;   // COMPAT/sqrt(HD) / ln2

// single-instruction f32x2 -> packed bf16x2 (RNE)
__device__ __forceinline__ unsigned pack2(float lo, float hi) {
    unsigned r;
    asm("v_cvt_pk_bf16_f32 %0, %1, %2" : "=v"(r) : "v"(lo), "v"(hi));
    return r;
}
__device__ __forceinline__ u16 f2bf(float x) {
    return (u16)pack2(x, x);
}
__device__ __forceinline__ float bf2f(u16 h) {
    union { unsigned u; float f; } v; v.u = ((unsigned)h) << 16;
    return v.f;
}
__device__ __forceinline__ float fexp2(float x) {   // 2^x
    float r;
    asm("v_exp_f32 %0, %1" : "=v"(r) : "v"(x));
    return r;
}
__device__ __forceinline__ float max3f(float a, float b, float c) {
    float r;
    asm("v_max3_f32 %0, %1, %2, %3" : "=v"(r) : "v"(a), "v"(b), "v"(c));
    return r;
}

// counted-wait + raw barrier (T4): leaves N vector-loads in flight.
#define GWAITBAR(N) do { \
    asm volatile("s_waitcnt vmcnt(" #N ") lgkmcnt(0)" ::: "memory"); \
    __builtin_amdgcn_sched_barrier(0); \
    __builtin_amdgcn_s_barrier(); \
    __builtin_amdgcn_sched_barrier(0); } while (0)

// async global->LDS 16B
typedef __attribute__((address_space(3))) unsigned int lds_u32;
typedef const __attribute__((address_space(1))) unsigned int glob_u32;
__device__ __forceinline__ void g2l16(void* l, const void* g) {
    __builtin_amdgcn_global_load_lds((glob_u32*)g, (lds_u32*)l, 16, 0, 0);
}

// ---------------------------------------------------------------------------
// mask mode detect (int32 / f32 / bytes)
__device__ __forceinline__ int is_valid(const void* mask, int mode, int idx) {
    if (mode == 0) return ((const int*)mask)[idx] != 0;
    if (mode == 1) return ((const float*)mask)[idx] != 0.0f;
    return ((const unsigned char*)mask)[idx] != 0;
}

// ---------------------------------------------------------------------------
// prep_k: mode-detect + 6x weight transpose/convert + front transpose
// + sat f32->bf16 + plucker MLP hidden + head weight folds:
// wsig = Wpl2@sig_w (512), wdbfT[h][k] = (Wpl2@db_w)^T, dbwT[h][n] = db_w^T,
// offs = pl_b2-dot offsets.
__global__ __launch_bounds__(256) void prep_k(
    const float* __restrict__ ff, const float* __restrict__ sat,
    const float* __restrict__ pl,
    const float* a0, const float* a1, const float* a2, const float* a3,
    const float* a4, const float* a5, u16* __restrict__ WT,
    u16* __restrict__ ffb, u16* __restrict__ satb,
    const float* __restrict__ plw1, const float* __restrict__ plb1,
    u16* __restrict__ plh,
    const unsigned* __restrict__ maskw, int* __restrict__ mode,
    float* __restrict__ scal,
    const float* __restrict__ plw2, const float* __restrict__ sigw,
    const float* __restrict__ dbw, const float* __restrict__ plb2,
    float* __restrict__ wsig, float* __restrict__ wdbfT,
    float* __restrict__ offs, float* __restrict__ dbwT) {
    __shared__ float tile[32][33];
    int blk = blockIdx.x, tid = threadIdx.x;
    if (blk < 4096) {                       // front_feat (B,C,T) -> (B*T,C) bf16
        int t0 = (blk & 31) * 32, c0 = ((blk >> 5) & 15) * 32, b = blk >> 9;
        int tx = tid & 31, ty = tid >> 5;
        const float* ip = ff + (size_t)b * C_ * T_;
        for (int i = ty; i < 32; i += 8)
            tile[i][tx] = ip[(size_t)(c0 + i) * T_ + t0 + tx];
        __syncthreads();
        u16* op = ffb + (size_t)b * T_ * C_;
        for (int i = ty; i < 32; i += 8)
            op[(size_t)(t0 + i) * C_ + c0 + tx] = f2bf(tile[tx][i]);
    } else if (blk < 5632) {                // weight W[k][n] -> Wt[n][k] bf16
        int idx = blk - 4096;
        const float* srcs[6] = {a0, a1, a2, a3, a4, a5};
        int z = idx >> 8;
        const float* src = srcs[z];
        u16* d = WT + (size_t)z * 512 * 512;
        int k0 = (idx & 15) * 32, n0 = ((idx >> 4) & 15) * 32;
        int tx = tid & 31, ty = tid >> 5;
        for (int i = ty; i < 32; i += 8)
            tile[i][tx] = src[(size_t)(k0 + i) * 512 + n0 + tx];
        __syncthreads();
        for (int i = ty; i < 32; i += 8)
            d[(size_t)(n0 + i) * 512 + k0 + tx] = f2bf(tile[tx][i]);
    } else if (blk < 7680) {                // sat f32 -> bf16 (x8 per thread)
        int i = (blk - 5632) * 256 + tid;
        const float4* p = (const float4*)(sat + (size_t)i * 8);
        float4 a = p[0], b = p[1];
        uint4 o;
        o.x = pack2(a.x, a.y); o.y = pack2(a.z, a.w);
        o.z = pack2(b.x, b.y); o.w = pack2(b.z, b.w);
        *(uint4*)(satb + (size_t)i * 8) = o;
    } else if (blk < 9728) {                // plucker hidden: silu MLP (K=6)
        int m = (blk - 7680) * 4 + (tid >> 6);
        int lane = tid & 63;
        float p6[6];
#pragma unroll
        for (int j = 0; j < 6; ++j) p6[j] = pl[(size_t)m * 6 + j];
        int n0 = lane * 8;
        float acc[8];
#pragma unroll
        for (int e = 0; e < 8; ++e) acc[e] = plb1[n0 + e];
#pragma unroll
        for (int j = 0; j < 6; ++j) {
            float4 wv0 = *(const float4*)(plw1 + j * D_ + n0);
            float4 wv1 = *(const float4*)(plw1 + j * D_ + n0 + 4);
            acc[0] += p6[j] * wv0.x; acc[1] += p6[j] * wv0.y;
            acc[2] += p6[j] * wv0.z; acc[3] += p6[j] * wv0.w;
            acc[4] += p6[j] * wv1.x; acc[5] += p6[j] * wv1.y;
            acc[6] += p6[j] * wv1.z; acc[7] += p6[j] * wv1.w;
        }
        uint4 o;
        float s0 = acc[0] / (1.0f + __expf(-acc[0]));
        float s1 = acc[1] / (1.0f + __expf(-acc[1]));
        float s2 = acc[2] / (1.0f + __expf(-acc[2]));
        float s3 = acc[3] / (1.0f + __expf(-acc[3]));
        float s4 = acc[4] / (1.0f + __expf(-acc[4]));
        float s5 = acc[5] / (1.0f + __expf(-acc[5]));
        float s6 = acc[6] / (1.0f + __expf(-acc[6]));
        float s7 = acc[7] / (1.0f + __expf(-acc[7]));
        o.x = pack2(s0, s1); o.y = pack2(s2, s3);
        o.z = pack2(s4, s5); o.w = pack2(s6, s7);
        *(uint4*)(plh + (size_t)m * D_ + n0) = o;
    } else if (blk == 9728) {               // mode detect + zero accumulators
        __shared__ int bad_i, bad_f;
        if (tid == 0) { bad_i = 0; bad_f = 0; }
        __syncthreads();
        for (int i = tid; i < 2048; i += 256) {
            unsigned v = maskw[i];
            if (v > 1u) bad_i = 1;
            if (v != 0u && v != 0x3f800000u) bad_f = 1;
        }
        __syncthreads();
        if (tid == 0) {
            *mode = (!bad_i) ? 0 : ((!bad_f) ? 1 : 2);
            scal[0] = 0.0f; scal[1] = 0.0f;
        }
    } else if (blk < 9731) {                // wsig[k] = sum_n plw2[k][n]*sigw[n]
        int k = (blk - 9729) * 256 + tid;
        const float* wr = plw2 + (size_t)k * 512;
        float acc = 0;
        for (int n = 0; n < 512; n += 4) {
            float4 wv = *(const float4*)(wr + n);
            float4 sv = *(const float4*)(sigw + n);
            acc += wv.x * sv.x + wv.y * sv.y + wv.z * sv.z + wv.w * sv.w;
        }
        wsig[k] = acc;
    } else if (blk < 9747) {                // wdbfT[h][k] = sum_n plw2[k][n]*dbw[n][h]
        int idx = blk - 9731;
        int k = idx * 32 + (tid >> 3), h = tid & 7;
        const float* wr = plw2 + (size_t)k * 512;
        float acc = 0;
        for (int n = 0; n < 512; ++n) acc += wr[n] * dbw[n * 8 + h];
        wdbfT[h * 512 + k] = acc;
    } else if (blk == 9747) {               // offs: pl_b2 dotted with heads
        float p = plb2[tid] * sigw[tid] + plb2[tid + 256] * sigw[tid + 256];
        float ph[8];
#pragma unroll
        for (int h = 0; h < 8; ++h)
            ph[h] = plb2[tid] * dbw[tid * 8 + h] +
                    plb2[tid + 256] * dbw[(tid + 256) * 8 + h];
        for (int o = 32; o; o >>= 1) {
            p += __shfl_down(p, o);
#pragma unroll
            for (int h = 0; h < 8; ++h) ph[h] += __shfl_down(ph[h], o);
        }
        __shared__ float red[4][9];
        int wv = tid >> 6, lane = tid & 63;
        if (lane == 0) {
            red[wv][0] = p;
#pragma unroll
            for (int h = 0; h < 8; ++h) red[wv][1 + h] = ph[h];
        }
        __syncthreads();
        if (tid == 0) {
            for (int j = 0; j < 9; ++j) {
                float t = 0;
                for (int v2 = 0; v2 < 4; ++v2) t += red[v2][j];
                offs[j] = t;
            }
        }
    } else {                                // dbwT[h][n] = dbw[n][h]
        for (int i = tid; i < 4096; i += 256) {
            int h = i >> 9, n = i & 511;
            dbwT[h * 512 + n] = dbw[n * 8 + h];
        }
    }
}

// ---------------------------------------------------------------------------
// Generic multi-job bf16 MFMA GEMM. Tile 128x128, 4 waves (each 64x64),
// BK=32, 16 MFMA/wave/step. 3-buffer depth-2 prefetch with counted vmcnt(8).
// Modes: 0 bf16 plain; 1 bf16*QSCALE2; 3 Vt bf16 transposed scatter.
__global__ __launch_bounds__(256) void gmm_k(
    const u16* __restrict__ A0, const u16* __restrict__ A1,
    const u16* __restrict__ A2,
    const u16* __restrict__ Bt0, const u16* __restrict__ Bt1,
    const u16* __restrict__ Bt2,
    const float* __restrict__ bb0, const float* __restrict__ bb1,
    const float* __restrict__ bb2,
    void* __restrict__ C0v, void* __restrict__ C1v, void* __restrict__ C2v,
    int md0, int md1, int md2) {
    __shared__ u16 As[3][4096];   // 8 KB each
    __shared__ u16 Bs[3][4096];   // 8 KB each
    int jid = blockIdx.x >> 8;
    int L = blockIdx.x & 255;
    const u16* A    = (jid == 0) ? A0 : (jid == 1) ? A1 : A2;
    const u16* Bt   = (jid == 0) ? Bt0 : (jid == 1) ? Bt1 : Bt2;
    const float* bias = (jid == 0) ? bb0 : (jid == 1) ? bb1 : bb2;
    void* Cv        = (jid == 0) ? C0v : (jid == 1) ? C1v : C2v;
    int mode        = (jid == 0) ? md0 : (jid == 1) ? md1 : md2;

    int tid = threadIdx.x, w = tid >> 6, l = tid & 63;
    int lr = l & 15, g = l >> 4;
    int W = (L & 7) * 32 + (L >> 3);          // XCD swizzle (256 % 8 == 0)
    int m0 = (W >> 2) * 128, n0 = (W & 3) * 128;
    int wr = w >> 1, wc = w & 1;
    int prm = g ^ ((lr >> 1) & 3);            // LDS read granule permutation

    f32x4 acc[4][4] = {};

    auto stage = [&](int buf, int k0) {
#pragma unroll
        for (int j = 0; j < 2; ++j) {          // A: 512 granules
            int i = tid + 256 * j;
            int row = i >> 2, gg = (i & 3) ^ ((i >> 3) & 3);
            g2l16((char*)As[buf] + (size_t)i * 16,
                  A + (size_t)(m0 + row) * 512 + k0 + gg * 8);
        }
#pragma unroll
        for (int j = 0; j < 2; ++j) {          // B: 512 granules
            int i = tid + 256 * j;
            int col = i >> 2, gg = (i & 3) ^ ((i >> 3) & 3);
            g2l16((char*)Bs[buf] + (size_t)i * 16,
                  Bt + (size_t)(n0 + col) * 512 + k0 + gg * 8);
        }
    };

    auto compute = [&](int bi) {
        const char* Ab = (const char*)As[bi];
        const char* Bb = (const char*)Bs[bi];
        short8 af[4], bf[4];
#pragma unroll
        for (int m = 0; m < 4; ++m)
            af[m] = *(const short8*)(Ab + ((wr * 64 + m * 16 + lr) * 4 + prm) * 16);
#pragma unroll
        for (int n = 0; n < 4; ++n)
            bf[n] = *(const short8*)(Bb + ((wc * 64 + n * 16 + lr) * 4 + prm) * 16);
        __builtin_amdgcn_s_setprio(1);
#pragma unroll
        for (int m = 0; m < 4; ++m)
#pragma unroll
            for (int n = 0; n < 4; ++n)
                acc[m][n] = __builtin_amdgcn_mfma_f32_16x16x32_bf16(
                    af[m], bf[n], acc[m][n], 0, 0, 0);
        __builtin_amdgcn_s_setprio(0);
    };

    stage(0, 0);
    stage(1, 32);
    for (int t = 0; t < 14; ++t) {
        stage((t + 2) % 3, (t + 2) * 32);
        GWAITBAR(8);
        compute(t % 3);
        __builtin_amdgcn_s_barrier();
    }
    GWAITBAR(4);
    compute(2);
    GWAITBAR(0);
    compute(0);

    float bs[4];
#pragma unroll
    for (int n = 0; n < 4; ++n) bs[n] = bias[n0 + wc * 64 + n * 16 + lr];

#pragma unroll
    for (int m = 0; m < 4; ++m) {
#pragma unroll
        for (int n = 0; n < 4; ++n) {
            int R0  = m0 + wr * 64 + m * 16 + 4 * g;
            int col = n0 + wc * 64 + n * 16 + lr;
            if (mode == 3) {                   // Vt transposed scatter
                int bbx = R0 >> 10, ss = R0 & 1023, hh = col >> 6, dd = col & 63;
                uint2 pk;
                pk.x = pack2(acc[m][n][0] + bs[n], acc[m][n][1] + bs[n]);
                pk.y = pack2(acc[m][n][2] + bs[n], acc[m][n][3] + bs[n]);
                u16* dst = (u16*)Cv + ((size_t)(bbx * 8 + hh) * 64 + dd) * 1024 + ss;
                *(uint2*)dst = pk;
            } else {
#pragma unroll
                for (int j = 0; j < 4; ++j) {
                    int row = R0 + j;
                    float v = acc[m][n][j] + bs[n];
                    if (mode == 1) v *= QSCALE2;
                    ((u16*)Cv)[(size_t)row * 512 + col] = f2bf(v);
                }
            }
        }
    }
}

// ---------------------------------------------------------------------------
// rf64_k: RF GEMM, tile 128x64 (512 blocks -> 2/CU, 8 waves/CU), BK=32,
// 3-buffer counted vmcnt (3 loads/thread/stage -> waits 6/3/0). Fused
// transposed epilogue: out1 = rf, out0 = ff + conf*rf, with in-kernel
// confidence (from dbp) + outc write + invalid-loss atomics.
__global__ __launch_bounds__(256) void rf64_k(
    const u16* __restrict__ A, const u16* __restrict__ Bt,
    const float* __restrict__ bias, float* __restrict__ out0,
    const float* __restrict__ ffp, float* __restrict__ out1p,
    const float* __restrict__ dbpp, const void* __restrict__ maskp,
    const int* __restrict__ modep, float* __restrict__ outcp,
    float* __restrict__ scalp) {
    __shared__ u16 As[3][4096];   // 8 KB each
    __shared__ u16 Bs[3][2048];   // 4 KB each
    __shared__ float confL[128];
    int L = blockIdx.x;
    int W = (L & 7) * 64 + (L >> 3);          // XCD swizzle (512 % 8 == 0)
    int m0 = (W >> 3) * 128, n0 = (W & 7) * 64;
    int tid = threadIdx.x, w = tid >> 6, l = tid & 63;
    int lr = l & 15, g = l >> 4;
    int wr = w >> 1, wc = w & 1;
    int prm = g ^ ((lr >> 1) & 3);

    f32x4 acc[4][2] = {};

    // confidence for this block's 128 rows (before staging)
    if (tid < 128) {
        int row = m0 + tid;
        const float* dr = dbpp + (size_t)row * NH_;
        float s = 0;
#pragma unroll
        for (int h = 0; h < 8; ++h) s += dr[h];
        float cf = 1.0f - s * 0.125f;
        confL[tid] = cf;
        if ((W & 7) == 0) {
            outcp[row] = cf;
            int md = *modep;
            float invd = is_valid(maskp, md, row) ? 0.0f : 1.0f;
            float a = cf * invd, bsum = invd;
            for (int o = 32; o; o >>= 1) {
                a += __shfl_down(a, o);
                bsum += __shfl_down(bsum, o);
            }
            if ((tid & 63) == 0) {
                atomicAdd(&scalp[0], a);
                atomicAdd(&scalp[1], bsum);
            }
        }
    }

    auto stage = [&](int buf, int k0) {
#pragma unroll
        for (int j = 0; j < 2; ++j) {          // A: 512 granules
            int i = tid + 256 * j;
            int row = i >> 2, gg = (i & 3) ^ ((i >> 3) & 3);
            g2l16((char*)As[buf] + (size_t)i * 16,
                  A + (size_t)(m0 + row) * 512 + k0 + gg * 8);
        }
        {                                      // B: 256 granules
            int col = tid >> 2, gg = (tid & 3) ^ ((tid >> 3) & 3);
            g2l16((char*)Bs[buf] + (size_t)tid * 16,
                  Bt + (size_t)(n0 + col) * 512 + k0 + gg * 8);
        }
    };

    auto compute = [&](int bi) {
        const char* Ab = (const char*)As[bi];
        const char* Bb = (const char*)Bs[bi];
        short8 af[4], bf[2];
#pragma unroll
        for (int m = 0; m < 4; ++m)
            af[m] = *(const short8*)(Ab + ((wr * 64 + m * 16 + lr) * 4 + prm) * 16);
#pragma unroll
        for (int n = 0; n < 2; ++n)
            bf[n] = *(const short8*)(Bb + ((wc * 32 + n * 16 + lr) * 4 + prm) * 16);
        __builtin_amdgcn_s_setprio(1);
#pragma unroll
        for (int m = 0; m < 4; ++m)
#pragma unroll
            for (int n = 0; n < 2; ++n)
                acc[m][n] = __builtin_amdgcn_mfma_f32_16x16x32_bf16(
                    af[m], bf[n], acc[m][n], 0, 0, 0);
        __builtin_amdgcn_s_setprio(0);
    };

    stage(0, 0);
    stage(1, 32);
    for (int t = 0; t < 14; ++t) {
        stage((t + 2) % 3, (t + 2) * 32);
        GWAITBAR(6);
        compute(t % 3);
        __builtin_amdgcn_s_barrier();
    }
    GWAITBAR(3);
    compute(2);
    GWAITBAR(0);
    compute(0);

    float bs[2] = {bias[n0 + wc * 32 + lr], bias[n0 + wc * 32 + 16 + lr]};
#pragma unroll
    for (int m = 0; m < 4; ++m)
#pragma unroll
        for (int n = 0; n < 2; ++n) {
            int R0  = m0 + wr * 64 + m * 16 + 4 * g;
            int col = n0 + wc * 32 + n * 16 + lr;
            int bbx = R0 >> 10, t0p = R0 & 1023;
            size_t base = (size_t)bbx * C_ * T_ + (size_t)col * T_ + t0p;
            float4 rf;
            rf.x = acc[m][n][0] + bs[n]; rf.y = acc[m][n][1] + bs[n];
            rf.z = acc[m][n][2] + bs[n]; rf.w = acc[m][n][3] + bs[n];
            float4 ffv = *(const float4*)(ffp + base);
            float4 cfv = *(const float4*)&confL[R0 - m0];
            float4 o0v;
            o0v.x = ffv.x + cfv.x * rf.x; o0v.y = ffv.y + cfv.y * rf.y;
            o0v.z = ffv.z + cfv.z * rf.z; o0v.w = ffv.w + cfv.w * rf.w;
            *(float4*)(out1p + base) = rf;
            *(float4*)(out0 + base) = o0v;
        }
}

// ---------------------------------------------------------------------------
// ln2h_k: merged LayerNorms (E and SE) + sigma/dustbin heads fused into the
// E branch (reuses the freshly-computed LN row + coalesced transposed
// weights). grid 16384: sel = blk>>13.
__global__ __launch_bounds__(256) void ln2h_k(
    const u16* __restrict__ X0, const float* __restrict__ g0,
    const float* __restrict__ b0, u16* __restrict__ O0,
    const u16* __restrict__ X1, const float* __restrict__ g1,
    const float* __restrict__ b1, u16* __restrict__ O1,
    const u16* __restrict__ PLH,
    const float* __restrict__ sigw, const float* __restrict__ sigb,
    const float* __restrict__ wsig, const float* __restrict__ dbwT,
    const float* __restrict__ wdbfT, const float* __restrict__ dbb,
    const float* __restrict__ offs,
    float* __restrict__ sigma, float* __restrict__ dbo) {
    int sel = blockIdx.x >> 13;
    int row = blockIdx.x & 8191;
    const u16* X = sel ? X1 : X0;
    const float* gw = sel ? g1 : g0;
    const float* bw = sel ? b1 : b0;
    u16* out = sel ? O1 : O0;
    int tid = threadIdx.x;
    const unsigned* xr = (const unsigned*)(X + (size_t)row * D_);
    unsigned u = xr[tid];
    float x0 = bf2f((u16)(u & 0xffff)), x1 = bf2f((u16)(u >> 16));
    float s = x0 + x1, sq = x0 * x0 + x1 * x1;
    __shared__ float rs[4], rq[4];
    __shared__ float hred[4][9];
    for (int o = 32; o; o >>= 1) { s += __shfl_down(s, o); sq += __shfl_down(sq, o); }
    int wid = tid >> 6, lane = tid & 63;
    if (lane == 0) { rs[wid] = s; rq[wid] = sq; }
    __syncthreads();
    if (tid == 0) {
        float ts = 0, tq = 0;
        for (int w = 0; w < 4; ++w) { ts += rs[w]; tq += rq[w]; }
        rs[0] = ts; rq[0] = tq;
    }
    __syncthreads();
    float mean = rs[0] * (1.0f / D_);
    float var  = rq[0] * (1.0f / D_) - mean * mean;
    float r = rsqrtf(var + 1e-5f);
    float2 g2 = *(const float2*)(gw + 2 * tid);
    float2 b2 = *(const float2*)(bw + 2 * tid);
    float y0 = (x0 - mean) * r * g2.x + b2.x;
    float y1 = (x1 - mean) * r * g2.y + b2.y;
    ((unsigned*)(out + (size_t)row * D_))[tid] = pack2(y0, y1);

    if (sel == 0) {
        // heads from E (y0,y1 in-register) + PLH (1 u32 load)
        unsigned upl = ((const unsigned*)(PLH + (size_t)row * D_))[tid];
        float pl0 = bf2f((u16)(upl & 0xffff)), pl1 = bf2f((u16)(upl >> 16));
        float2 sw = *(const float2*)(sigw + 2 * tid);
        float2 fw = *(const float2*)(wsig + 2 * tid);
        float sacc = y0 * sw.x + y1 * sw.y + pl0 * fw.x + pl1 * fw.y;
        float d_[8];
#pragma unroll
        for (int h = 0; h < 8; ++h) {
            float2 av = *(const float2*)(dbwT + h * 512 + 2 * tid);
            float2 bv = *(const float2*)(wdbfT + h * 512 + 2 * tid);
            d_[h] = y0 * av.x + y1 * av.y + pl0 * bv.x + pl1 * bv.y;
        }
        for (int o = 32; o; o >>= 1) {
            sacc += __shfl_down(sacc, o);
#pragma unroll
            for (int h = 0; h < 8; ++h) d_[h] += __shfl_down(d_[h], o);
        }
        if (lane == 0) {
            hred[wid][0] = sacc;
#pragma unroll
            for (int h = 0; h < 8; ++h) hred[wid][1 + h] = d_[h];
        }
        __syncthreads();
        if (tid == 0) {
            float t0 = hred[0][0] + hred[1][0] + hred[2][0] + hred[3][0];
            float z = t0 + sigb[0] + offs[0];
            sigma[row] = 0.03f + 0.32f / (1.0f + __expf(-z));
            float* dd = dbo + (size_t)row * NH_;
#pragma unroll
            for (int h = 0; h < 8; ++h) {
                float th = hred[0][1 + h] + hred[1][1 + h] +
                           hred[2][1 + h] + hred[3][1 + h];
                dd[h] = th + dbb[h] + offs[1 + h];
            }
        }
    }
}

// ---------------------------------------------------------------------------
// Staged MFMA flash attention, KVBLK=64, exp2 softmax, 512-thread blocks.
// Issue-then-counted-wait staging (vmcnt(2)); -m_st folded into AbaseM;
// cross-lane max only in rescale branch; l-sum via ones-row MFMA; max3 tree.
// P stays in registers via bit-permuted K staging. 44 KB LDS.
__global__ __launch_bounds__(512) void attn_k(
    const u16* __restrict__ Q, const u16* __restrict__ K,
    const u16* __restrict__ Vt, const float* __restrict__ sig,
    const float* __restrict__ dbl, const float* __restrict__ bev,
    const float* __restrict__ sxy, const void* __restrict__ mask,
    const int* __restrict__ mode, u16* __restrict__ OUT,
    float* __restrict__ dbp) {
    int L = blockIdx.x;
    int W = (L & 7) * 64 + (L >> 3);   // XCD swizzle
    int b = W >> 6, h = (W >> 3) & 7, tblk = W & 7;
    int tid = threadIdx.x, w = tid >> 6, l = tid & 63;
    int lr = l & 15, g = l >> 4;
    int p8 = lr & 7;                   // LDS read granule permutation

    __shared__ u16 Kbuf[2][4096];      // 8 KB each
    __shared__ u16 Vbuf[2][4096];      // 8 KB each
    __shared__ float2 SXY[1024];       // (-2x, -2y)
    __shared__ float  SZ[1024];        // x^2+y^2

    const float2* xp = (const float2*)(sxy + (size_t)b * S_ * 2);
#pragma unroll
    for (int j = 0; j < 2; ++j) {
        int idx = tid + 512 * j;
        float2 v = xp[idx];
        SXY[idx] = make_float2(-2.0f * v.x, -2.0f * v.y);
        SZ[idx] = v.x * v.x + v.y * v.y;
    }

    int trow = b * T_ + tblk * 128 + w * 16 + lr;
    float s_ = sig[trow];
    float bx = bev[(size_t)trow * 2], by = bev[(size_t)trow * 2 + 1];
    float dbv2 = dbl[(size_t)trow * NH_ + h] * INVLN2;
    int md = *mode;
    bool vld = is_valid(mask, md, trow) != 0;
    float grow  = vld ? (-11.5415603271117f / fmaxf(s_ * s_, 1e-6f)) : 0.0f;
    float Abase = vld ? grow * (bx * bx + by * by) : -10000.0f;
    float AbaseM = Abase - dbv2;       // Abase - m_st, maintained across chunks
    float mshift = 0.0f;               // dbv2 - m_st

    const u16* qp = Q + (size_t)trow * 512 + h * 64 + g * 8;
    short8 q0 = *(const short8*)qp;
    short8 q1 = *(const short8*)(qp + 32);
    if (!vld) { q0 = short8{}; q1 = short8{}; }

    short8 ones;
#pragma unroll
    for (int e = 0; e < 8; ++e) ones[e] = (short)0x3F80;   // bf16 1.0

    const u16* Kp = K + (size_t)b * S_ * 512 + h * 64;
    const u16* Vp = Vt + (size_t)(b * 8 + h) * 64 * 1024;

    // staging indices: slot row = tid>>3, permuted granule
    int srow = tid >> 3;                           // 0..63
    int gprm = (tid & 7) ^ (srow & 7);
    // K source row via sigma bit-permutation of the slot row
    int sK = ((srow >> 5) & 1) * 32 + ((srow >> 2) & 3) * 8 +
             ((srow >> 4) & 1) * 4 + (srow & 3);

    auto stageKV = [&](int buf, int s0) {
        g2l16((char*)Kbuf[buf] + (size_t)tid * 16,
              Kp + (size_t)(s0 + sK) * 512 + gprm * 8);
        g2l16((char*)Vbuf[buf] + (size_t)tid * 16,
              Vp + (size_t)srow * 1024 + s0 + gprm * 8);
    };

    f32x4 o0 = {}, o1 = {}, o2 = {}, o3 = {};
    f32x4 o4 = {1.0f, 1.0f, 1.0f, 1.0f};   // l-accumulator (dustbin term = 1)

    stageKV(0, 0);
    int cur = 0;
    for (int c = 0; c < 16; ++c) {
        int s0c = c * 64;
        if (c < 15) {
            stageKV(cur ^ 1, s0c + 64);
            GWAITBAR(2);               // chunk c landed; next chunk in flight
        } else {
            GWAITBAR(0);
        }

        const char* Kc = (const char*)Kbuf[cur];
        const char* Vc = (const char*)Vbuf[cur];

        f32x4 p[4];
        f32x4 z4 = {};
        __builtin_amdgcn_s_setprio(1);
#pragma unroll
        for (int sub = 0; sub < 4; ++sub) {
            int krow = sub * 16 + lr;
            short8 kf0 = *(const short8*)(Kc + (krow * 8 + (g ^ p8)) * 16);
            short8 kf1 = *(const short8*)(Kc + (krow * 8 + ((4 + g) ^ p8)) * 16);
            p[sub] = __builtin_amdgcn_mfma_f32_16x16x32_bf16(kf0, q0, z4, 0, 0, 0);
            p[sub] = __builtin_amdgcn_mfma_f32_16x16x32_bf16(kf1, q1, p[sub], 0, 0, 0);
        }
        __builtin_amdgcn_s_setprio(0);

        // logits, already max-shifted: lg = raw - m_st
        float lg[16];
#pragma unroll
        for (int sub = 0; sub < 4; ++sub) {
            int sl = s0c + ((sub & 2) << 4) + 8 * g + ((sub & 1) << 2);
            float4 xy01 = *(const float4*)&SXY[sl];
            float4 xy23 = *(const float4*)&SXY[sl + 2];
            float4 zz   = *(const float4*)&SZ[sl];
            float X[4] = {xy01.x, xy01.z, xy23.x, xy23.z};
            float Y[4] = {xy01.y, xy01.w, xy23.y, xy23.w};
            float Z[4] = {zz.x, zz.y, zz.z, zz.w};
#pragma unroll
            for (int i2 = 0; i2 < 4; ++i2) {
                float wg = fmaf(bx, X[i2], fmaf(by, Y[i2], Z[i2]));
                lg[sub * 4 + i2] = fmaf(grow, wg, p[sub][i2] + AbaseM);
            }
        }
        // local max via max3 tree
        float c0 = max3f(lg[0], lg[1], lg[2]);
        float c1 = max3f(lg[3], lg[4], lg[5]);
        float c2 = max3f(lg[6], lg[7], lg[8]);
        float c3 = max3f(lg[9], lg[10], lg[11]);
        float c4 = max3f(lg[12], lg[13], lg[14]);
        float cl = fmaxf(max3f(c0, c1, c2), max3f(c3, c4, lg[15]));

        if (!__all(cl <= 11.5f)) {            // rare: true max exceeds m_st+THR
            cl = fmaxf(cl, __shfl_xor(cl, 16));
            cl = fmaxf(cl, __shfl_xor(cl, 32));
            float dm = fmaxf(cl, 0.0f);       // m_new - m_st
            float scl = fexp2(-dm);
            o0 *= scl; o1 *= scl; o2 *= scl; o3 *= scl; o4 *= scl;
            AbaseM -= dm;
            mshift -= dm;
#pragma unroll
            for (int r = 0; r < 16; ++r) lg[r] -= dm;
        }
        float pe[16];
#pragma unroll
        for (int r = 0; r < 16; ++r) pe[r] = fexp2(lg[r]);

        union { uint4 u; short8 s8; } pf0, pf1;
        pf0.u.x = pack2(pe[0], pe[1]);  pf0.u.y = pack2(pe[2], pe[3]);
        pf0.u.z = pack2(pe[4], pe[5]);  pf0.u.w = pack2(pe[6], pe[7]);
        pf1.u.x = pack2(pe[8], pe[9]);  pf1.u.y = pack2(pe[10], pe[11]);
        pf1.u.z = pack2(pe[12], pe[13]); pf1.u.w = pack2(pe[14], pe[15]);

        __builtin_amdgcn_s_setprio(1);
        short8 vf;
#pragma unroll
        for (int dt = 0; dt < 4; ++dt) {
            int vrow = dt * 16 + lr;
            f32x4* oo = (dt == 0) ? &o0 : (dt == 1) ? &o1 : (dt == 2) ? &o2 : &o3;
            vf = *(const short8*)(Vc + (vrow * 8 + (g ^ p8)) * 16);
            *oo = __builtin_amdgcn_mfma_f32_16x16x32_bf16(vf, pf0.s8, *oo, 0, 0, 0);
            vf = *(const short8*)(Vc + (vrow * 8 + ((4 + g) ^ p8)) * 16);
            *oo = __builtin_amdgcn_mfma_f32_16x16x32_bf16(vf, pf1.s8, *oo, 0, 0, 0);
        }
        // l-sum on the matrix pipe: ones-row x P
        o4 = __builtin_amdgcn_mfma_f32_16x16x32_bf16(ones, pf0.s8, o4, 0, 0, 0);
        o4 = __builtin_amdgcn_mfma_f32_16x16x32_bf16(ones, pf1.s8, o4, 0, 0, 0);
        __builtin_amdgcn_s_setprio(0);

        __builtin_amdgcn_s_barrier();   // all reads of buf cur done before reuse
        cur ^= 1;
    }

    float inv = 1.0f / o4[0];
    u16* ob = OUT + (size_t)trow * 512 + h * 64;
    {
        uint2 pk;
        pk.x = pack2(o0[0] * inv, o0[1] * inv); pk.y = pack2(o0[2] * inv, o0[3] * inv);
        *(uint2*)(ob + 0 * 16 + 4 * g) = pk;
        pk.x = pack2(o1[0] * inv, o1[1] * inv); pk.y = pack2(o1[2] * inv, o1[3] * inv);
        *(uint2*)(ob + 1 * 16 + 4 * g) = pk;
        pk.x = pack2(o2[0] * inv, o2[1] * inv); pk.y = pack2(o2[2] * inv, o2[3] * inv);
        *(uint2*)(ob + 2 * 16 + 4 * g) = pk;
        pk.x = pack2(o3[0] * inv, o3[1] * inv); pk.y = pack2(o3[2] * inv, o3[3] * inv);
        *(uint2*)(ob + 3 * 16 + 4 * g) = pk;
    }
    if (g == 0) dbp[(size_t)trow * NH_ + h] = fexp2(mshift) * inv;
}

__global__ void loss_k(const float* __restrict__ scal, float* __restrict__ out) {
    out[0] = scal[0] / fmaxf(scal[1], 1.0f) * 0.05f;
}

// ---------------------------------------------------------------------------
extern "C" void kernel_launch(void* const* d_in, const int* in_sizes, int n_in,
                              void* d_out, int out_size, void* d_ws, size_t ws_size,
                              hipStream_t stream) {
    const float* front_feat = (const float*)d_in[0];
    const float* sat_tokens = (const float*)d_in[1];
    const float* sat_xy     = (const float*)d_in[2];
    const float* bev_xy     = (const float*)d_in[3];
    const void*  mask       = d_in[4];
    const float* plucker    = (const float*)d_in[5];
    const float* fa_w = (const float*)d_in[6];
    const float* fa_b = (const float*)d_in[7];
    const float* fa_g = (const float*)d_in[8];
    const float* fa_lb = (const float*)d_in[9];
    const float* sa_w = (const float*)d_in[10];
    const float* sa_b = (const float*)d_in[11];
    const float* sa_g = (const float*)d_in[12];
    const float* sa_lb = (const float*)d_in[13];
    const float* q_w = (const float*)d_in[14];
    const float* q_b = (const float*)d_in[15];
    const float* k_w = (const float*)d_in[16];
    const float* k_b = (const float*)d_in[17];
    const float* v_w = (const float*)d_in[18];
    const float* v_b = (const float*)d_in[19];
    const float* pl_w1 = (const float*)d_in[20];
    const float* pl_b1 = (const float*)d_in[21];
    const float* pl_w2 = (const float*)d_in[22];
    const float* pl_b2 = (const float*)d_in[23];
    const float* sig_w = (const float*)d_in[24];
    const float* sig_b = (const float*)d_in[25];
    const float* db_w = (const float*)d_in[26];
    const float* db_b = (const float*)d_in[27];
    const float* out_w = (const float*)d_in[28];
    const float* out_b = (const float*)d_in[29];

    char* w8 = (char*)d_ws;
    u16* H0 = (u16*)(w8);                        // 8 MB bf16 slots
    u16* H1 = (u16*)(w8 + 8388608ull * 1);
    u16* H2 = (u16*)(w8 + 8388608ull * 2);
    u16* H3 = (u16*)(w8 + 8388608ull * 3);
    u16* H4 = (u16*)(w8 + 8388608ull * 4);
    u16* H5 = (u16*)(w8 + 8388608ull * 5);
    u16* H6 = (u16*)(w8 + 8388608ull * 6);
    u16* WT = (u16*)(w8 + 8388608ull * 7);       // 6 x 0.5 MB
    char* sm = w8 + 8388608ull * 7 + 3670016ull;
    float* w_sigma = (float*)sm;
    float* w_db    = w_sigma + BT_;
    float* w_dbp   = w_db + (size_t)BT_ * NH_;
    float* w_scal  = w_dbp + (size_t)BT_ * NH_;
    int*   w_mode  = (int*)(w_scal + 2);
    float* w_wsig  = w_scal + 4;                 // 512
    float* w_wdbfT = w_wsig + 512;               // 4096
    float* w_offs  = w_wdbfT + 4096;             // 9 (pad to 16)
    float* w_dbwT  = w_offs + 16;                // 4096

    u16* Wfa = WT;                 u16* Wq  = WT + 262144ull * 1;
    u16* Wsa = WT + 262144ull * 2; u16* Wk  = WT + 262144ull * 3;
    u16* Wv  = WT + 262144ull * 4; u16* Wo  = WT + 262144ull * 5;

    float* out0 = (float*)d_out;
    float* out1 = out0 + (size_t)B_ * C_ * T_;
    float* outc = out1 + (size_t)B_ * C_ * T_;
    float* outl = outc + (size_t)B_ * T_;

    dim3 blk(256);

    // 1. prep: mode + 6 weight transposes + front transpose (H0) + sat (H5)
    //    + plucker hidden (H2) + head weight folds (transposed layouts)
    prep_k<<<dim3(9749), blk, 0, stream>>>(
        front_feat, sat_tokens, plucker,
        fa_w, q_w, sa_w, k_w, v_w, out_w, WT,
        H0, H5, pl_w1, pl_b1, H2,
        (const unsigned*)mask, w_mode, w_scal,
        pl_w2, sig_w, db_w, pl_b2, w_wsig, w_wdbfT, w_offs, w_dbwT);
    // 2. E_pre (H0@Wfa -> H6) and SAT_pre (H5@Wsa -> H4), 512 blocks
    gmm_k<<<dim3(512), blk, 0, stream>>>(
        H0, H5, nullptr,
        Wfa, Wsa, nullptr,
        fa_b, sa_b, nullptr,
        H6, H4, nullptr,
        0, 0, 0);
    // 3. LN(E_pre)->H1, LN(SAT_pre)->H3, + fused sigma/dustbin heads
    ln2h_k<<<dim3(16384), blk, 0, stream>>>(
        H6, fa_g, fa_lb, H1,
        H4, sa_g, sa_lb, H3,
        H2, sig_w, sig_b, w_wsig, w_dbwT, w_wdbfT, db_b, w_offs,
        w_sigma, w_db);
    // 4. Q (H1->H5, scale), K (H3->H0), Vt (H3->H4 scatter), 768 blocks
    gmm_k<<<dim3(768), blk, 0, stream>>>(
        H1, H3, H3,
        Wq, Wk, Wv,
        q_b, k_b, v_b,
        H5, H0, H4,
        1, 0, 3);
    // 5. attention: Q=H5, K=H0, Vt=H4 -> OUT=H2
    attn_k<<<dim3(512), dim3(512), 0, stream>>>(
        H5, H0, H4, w_sigma, w_db, bev_xy, sat_xy, mask, w_mode, H2, w_dbp);
    // 6. RF = H2 @ Wo (128x64 tiles, 512 blocks), fused transposed epilogue
    //    + in-kernel confidence/loss
    rf64_k<<<dim3(512), blk, 0, stream>>>(
        H2, Wo, out_b, out0, front_feat, out1,
        w_dbp, mask, w_mode, outc, w_scal);
    // 7. loss scalar
    loss_k<<<1, 1, 0, stream>>>(w_scal, outl);
}

// Round 16
// 150.580 us; speedup vs baseline: 1.0606x; 1.0606x over previous
//
#include <hip/hip_runtime.h>

typedef unsigned short u16;
typedef __attribute__((ext_vector_type(8))) short short8;   // 8 bf16 = 4 VGPR
typedef __attribute__((ext_vector_type(4))) float f32x4;    // MFMA acc

// Problem constants
constexpr int B_  = 8;
constexpr int C_  = 512;
constexpr int T_  = 1024;   // H*W
constexpr int S_  = 1024;
constexpr int D_  = 512;
constexpr int NH_ = 8;
constexpr int BT_ = B_ * T_;   // 8192
constexpr float INVLN2 = 1.44269504088896340736f;
constexpr float QSCALE2 = 0.0125f * INVLN2;   // COMPAT/sqrt(HD) / ln2

// single-instruction f32x2 -> packed bf16x2 (RNE)
__device__ __forceinline__ unsigned pack2(float lo, float hi) {
    unsigned r;
    asm("v_cvt_pk_bf16_f32 %0, %1, %2" : "=v"(r) : "v"(lo), "v"(hi));
    return r;
}
__device__ __forceinline__ u16 f2bf(float x) {
    return (u16)pack2(x, x);
}
__device__ __forceinline__ float bf2f(u16 h) {
    union { unsigned u; float f; } v; v.u = ((unsigned)h) << 16;
    return v.f;
}
__device__ __forceinline__ float fexp2(float x) {   // 2^x
    float r;
    asm("v_exp_f32 %0, %1" : "=v"(r) : "v"(x));
    return r;
}
__device__ __forceinline__ float max3f(float a, float b, float c) {
    float r;
    asm("v_max3_f32 %0, %1, %2, %3" : "=v"(r) : "v"(a), "v"(b), "v"(c));
    return r;
}

// counted-wait + raw barrier (T4): leaves N vector-loads in flight.
#define GWAITBAR(N) do { \
    asm volatile("s_waitcnt vmcnt(" #N ") lgkmcnt(0)" ::: "memory"); \
    __builtin_amdgcn_sched_barrier(0); \
    __builtin_amdgcn_s_barrier(); \
    __builtin_amdgcn_sched_barrier(0); } while (0)

// async global->LDS 16B
typedef __attribute__((address_space(3))) unsigned int lds_u32;
typedef const __attribute__((address_space(1))) unsigned int glob_u32;
__device__ __forceinline__ void g2l16(void* l, const void* g) {
    __builtin_amdgcn_global_load_lds((glob_u32*)g, (lds_u32*)l, 16, 0, 0);
}

// ---------------------------------------------------------------------------
// mask mode detect (int32 / f32 / bytes)
__device__ __forceinline__ int is_valid(const void* mask, int mode, int idx) {
    if (mode == 0) return ((const int*)mask)[idx] != 0;
    if (mode == 1) return ((const float*)mask)[idx] != 0.0f;
    return ((const unsigned char*)mask)[idx] != 0;
}

// ---------------------------------------------------------------------------
// prep_k: mode-detect + 6x weight transpose/convert + front transpose
// + sat f32->bf16 + plucker MLP hidden + head weight folds:
// wsig = Wpl2@sig_w (512), wdbfT[h][k] = (Wpl2@db_w)^T, dbwT[h][n] = db_w^T,
// offs = pl_b2-dot offsets.
__global__ __launch_bounds__(256) void prep_k(
    const float* __restrict__ ff, const float* __restrict__ sat,
    const float* __restrict__ pl,
    const float* a0, const float* a1, const float* a2, const float* a3,
    const float* a4, const float* a5, u16* __restrict__ WT,
    u16* __restrict__ ffb, u16* __restrict__ satb,
    const float* __restrict__ plw1, const float* __restrict__ plb1,
    u16* __restrict__ plh,
    const unsigned* __restrict__ maskw, int* __restrict__ mode,
    float* __restrict__ scal,
    const float* __restrict__ plw2, const float* __restrict__ sigw,
    const float* __restrict__ dbw, const float* __restrict__ plb2,
    float* __restrict__ wsig, float* __restrict__ wdbfT,
    float* __restrict__ offs, float* __restrict__ dbwT) {
    __shared__ float tile[32][33];
    int blk = blockIdx.x, tid = threadIdx.x;
    if (blk < 4096) {                       // front_feat (B,C,T) -> (B*T,C) bf16
        int t0 = (blk & 31) * 32, c0 = ((blk >> 5) & 15) * 32, b = blk >> 9;
        int tx = tid & 31, ty = tid >> 5;
        const float* ip = ff + (size_t)b * C_ * T_;
        for (int i = ty; i < 32; i += 8)
            tile[i][tx] = ip[(size_t)(c0 + i) * T_ + t0 + tx];
        __syncthreads();
        u16* op = ffb + (size_t)b * T_ * C_;
        for (int i = ty; i < 32; i += 8)
            op[(size_t)(t0 + i) * C_ + c0 + tx] = f2bf(tile[tx][i]);
    } else if (blk < 5632) {                // weight W[k][n] -> Wt[n][k] bf16
        int idx = blk - 4096;
        const float* srcs[6] = {a0, a1, a2, a3, a4, a5};
        int z = idx >> 8;
        const float* src = srcs[z];
        u16* d = WT + (size_t)z * 512 * 512;
        int k0 = (idx & 15) * 32, n0 = ((idx >> 4) & 15) * 32;
        int tx = tid & 31, ty = tid >> 5;
        for (int i = ty; i < 32; i += 8)
            tile[i][tx] = src[(size_t)(k0 + i) * 512 + n0 + tx];
        __syncthreads();
        for (int i = ty; i < 32; i += 8)
            d[(size_t)(n0 + i) * 512 + k0 + tx] = f2bf(tile[tx][i]);
    } else if (blk < 7680) {                // sat f32 -> bf16 (x8 per thread)
        int i = (blk - 5632) * 256 + tid;
        const float4* p = (const float4*)(sat + (size_t)i * 8);
        float4 a = p[0], b = p[1];
        uint4 o;
        o.x = pack2(a.x, a.y); o.y = pack2(a.z, a.w);
        o.z = pack2(b.x, b.y); o.w = pack2(b.z, b.w);
        *(uint4*)(satb + (size_t)i * 8) = o;
    } else if (blk < 9728) {                // plucker hidden: silu MLP (K=6)
        int m = (blk - 7680) * 4 + (tid >> 6);
        int lane = tid & 63;
        float p6[6];
#pragma unroll
        for (int j = 0; j < 6; ++j) p6[j] = pl[(size_t)m * 6 + j];
        int n0 = lane * 8;
        float acc[8];
#pragma unroll
        for (int e = 0; e < 8; ++e) acc[e] = plb1[n0 + e];
#pragma unroll
        for (int j = 0; j < 6; ++j) {
            float4 wv0 = *(const float4*)(plw1 + j * D_ + n0);
            float4 wv1 = *(const float4*)(plw1 + j * D_ + n0 + 4);
            acc[0] += p6[j] * wv0.x; acc[1] += p6[j] * wv0.y;
            acc[2] += p6[j] * wv0.z; acc[3] += p6[j] * wv0.w;
            acc[4] += p6[j] * wv1.x; acc[5] += p6[j] * wv1.y;
            acc[6] += p6[j] * wv1.z; acc[7] += p6[j] * wv1.w;
        }
        uint4 o;
        float s0 = acc[0] / (1.0f + __expf(-acc[0]));
        float s1 = acc[1] / (1.0f + __expf(-acc[1]));
        float s2 = acc[2] / (1.0f + __expf(-acc[2]));
        float s3 = acc[3] / (1.0f + __expf(-acc[3]));
        float s4 = acc[4] / (1.0f + __expf(-acc[4]));
        float s5 = acc[5] / (1.0f + __expf(-acc[5]));
        float s6 = acc[6] / (1.0f + __expf(-acc[6]));
        float s7 = acc[7] / (1.0f + __expf(-acc[7]));
        o.x = pack2(s0, s1); o.y = pack2(s2, s3);
        o.z = pack2(s4, s5); o.w = pack2(s6, s7);
        *(uint4*)(plh + (size_t)m * D_ + n0) = o;
    } else if (blk == 9728) {               // mode detect + zero accumulators
        __shared__ int bad_i, bad_f;
        if (tid == 0) { bad_i = 0; bad_f = 0; }
        __syncthreads();
        for (int i = tid; i < 2048; i += 256) {
            unsigned v = maskw[i];
            if (v > 1u) bad_i = 1;
            if (v != 0u && v != 0x3f800000u) bad_f = 1;
        }
        __syncthreads();
        if (tid == 0) {
            *mode = (!bad_i) ? 0 : ((!bad_f) ? 1 : 2);
            scal[0] = 0.0f; scal[1] = 0.0f;
        }
    } else if (blk < 9731) {                // wsig[k] = sum_n plw2[k][n]*sigw[n]
        int k = (blk - 9729) * 256 + tid;
        const float* wr = plw2 + (size_t)k * 512;
        float acc = 0;
        for (int n = 0; n < 512; n += 4) {
            float4 wv = *(const float4*)(wr + n);
            float4 sv = *(const float4*)(sigw + n);
            acc += wv.x * sv.x + wv.y * sv.y + wv.z * sv.z + wv.w * sv.w;
        }
        wsig[k] = acc;
    } else if (blk < 9747) {                // wdbfT[h][k] = sum_n plw2[k][n]*dbw[n][h]
        int idx = blk - 9731;
        int k = idx * 32 + (tid >> 3), h = tid & 7;
        const float* wr = plw2 + (size_t)k * 512;
        float acc = 0;
        for (int n = 0; n < 512; ++n) acc += wr[n] * dbw[n * 8 + h];
        wdbfT[h * 512 + k] = acc;
    } else if (blk == 9747) {               // offs: pl_b2 dotted with heads
        float p = plb2[tid] * sigw[tid] + plb2[tid + 256] * sigw[tid + 256];
        float ph[8];
#pragma unroll
        for (int h = 0; h < 8; ++h)
            ph[h] = plb2[tid] * dbw[tid * 8 + h] +
                    plb2[tid + 256] * dbw[(tid + 256) * 8 + h];
        for (int o = 32; o; o >>= 1) {
            p += __shfl_down(p, o);
#pragma unroll
            for (int h = 0; h < 8; ++h) ph[h] += __shfl_down(ph[h], o);
        }
        __shared__ float red[4][9];
        int wv = tid >> 6, lane = tid & 63;
        if (lane == 0) {
            red[wv][0] = p;
#pragma unroll
            for (int h = 0; h < 8; ++h) red[wv][1 + h] = ph[h];
        }
        __syncthreads();
        if (tid == 0) {
            for (int j = 0; j < 9; ++j) {
                float t = 0;
                for (int v2 = 0; v2 < 4; ++v2) t += red[v2][j];
                offs[j] = t;
            }
        }
    } else {                                // dbwT[h][n] = dbw[n][h]
        for (int i = tid; i < 4096; i += 256) {
            int h = i >> 9, n = i & 511;
            dbwT[h * 512 + n] = dbw[n * 8 + h];
        }
    }
}

// ---------------------------------------------------------------------------
// Generic multi-job bf16 MFMA GEMM. Tile 128x128, 4 waves (each 64x64),
// BK=32, 16 MFMA/wave/step. 3-buffer depth-2 prefetch with counted vmcnt(8).
// Modes: 0 bf16 plain; 1 bf16*QSCALE2; 3 Vt bf16 transposed scatter.
__global__ __launch_bounds__(256) void gmm_k(
    const u16* __restrict__ A0, const u16* __restrict__ A1,
    const u16* __restrict__ A2,
    const u16* __restrict__ Bt0, const u16* __restrict__ Bt1,
    const u16* __restrict__ Bt2,
    const float* __restrict__ bb0, const float* __restrict__ bb1,
    const float* __restrict__ bb2,
    void* __restrict__ C0v, void* __restrict__ C1v, void* __restrict__ C2v,
    int md0, int md1, int md2) {
    __shared__ u16 As[3][4096];   // 8 KB each
    __shared__ u16 Bs[3][4096];   // 8 KB each
    int jid = blockIdx.x >> 8;
    int L = blockIdx.x & 255;
    const u16* A    = (jid == 0) ? A0 : (jid == 1) ? A1 : A2;
    const u16* Bt   = (jid == 0) ? Bt0 : (jid == 1) ? Bt1 : Bt2;
    const float* bias = (jid == 0) ? bb0 : (jid == 1) ? bb1 : bb2;
    void* Cv        = (jid == 0) ? C0v : (jid == 1) ? C1v : C2v;
    int mode        = (jid == 0) ? md0 : (jid == 1) ? md1 : md2;

    int tid = threadIdx.x, w = tid >> 6, l = tid & 63;
    int lr = l & 15, g = l >> 4;
    int W = (L & 7) * 32 + (L >> 3);          // XCD swizzle (256 % 8 == 0)
    int m0 = (W >> 2) * 128, n0 = (W & 3) * 128;
    int wr = w >> 1, wc = w & 1;
    int prm = g ^ ((lr >> 1) & 3);            // LDS read granule permutation

    f32x4 acc[4][4] = {};

    auto stage = [&](int buf, int k0) {
#pragma unroll
        for (int j = 0; j < 2; ++j) {          // A: 512 granules
            int i = tid + 256 * j;
            int row = i >> 2, gg = (i & 3) ^ ((i >> 3) & 3);
            g2l16((char*)As[buf] + (size_t)i * 16,
                  A + (size_t)(m0 + row) * 512 + k0 + gg * 8);
        }
#pragma unroll
        for (int j = 0; j < 2; ++j) {          // B: 512 granules
            int i = tid + 256 * j;
            int col = i >> 2, gg = (i & 3) ^ ((i >> 3) & 3);
            g2l16((char*)Bs[buf] + (size_t)i * 16,
                  Bt + (size_t)(n0 + col) * 512 + k0 + gg * 8);
        }
    };

    auto compute = [&](int bi) {
        const char* Ab = (const char*)As[bi];
        const char* Bb = (const char*)Bs[bi];
        short8 af[4], bf[4];
#pragma unroll
        for (int m = 0; m < 4; ++m)
            af[m] = *(const short8*)(Ab + ((wr * 64 + m * 16 + lr) * 4 + prm) * 16);
#pragma unroll
        for (int n = 0; n < 4; ++n)
            bf[n] = *(const short8*)(Bb + ((wc * 64 + n * 16 + lr) * 4 + prm) * 16);
        __builtin_amdgcn_s_setprio(1);
#pragma unroll
        for (int m = 0; m < 4; ++m)
#pragma unroll
            for (int n = 0; n < 4; ++n)
                acc[m][n] = __builtin_amdgcn_mfma_f32_16x16x32_bf16(
                    af[m], bf[n], acc[m][n], 0, 0, 0);
        __builtin_amdgcn_s_setprio(0);
    };

    stage(0, 0);
    stage(1, 32);
    for (int t = 0; t < 14; ++t) {
        stage((t + 2) % 3, (t + 2) * 32);
        GWAITBAR(8);
        compute(t % 3);
        __builtin_amdgcn_s_barrier();
    }
    GWAITBAR(4);
    compute(2);
    GWAITBAR(0);
    compute(0);

    float bs[4];
#pragma unroll
    for (int n = 0; n < 4; ++n) bs[n] = bias[n0 + wc * 64 + n * 16 + lr];

#pragma unroll
    for (int m = 0; m < 4; ++m) {
#pragma unroll
        for (int n = 0; n < 4; ++n) {
            int R0  = m0 + wr * 64 + m * 16 + 4 * g;
            int col = n0 + wc * 64 + n * 16 + lr;
            if (mode == 3) {                   // Vt transposed scatter
                int bbx = R0 >> 10, ss = R0 & 1023, hh = col >> 6, dd = col & 63;
                uint2 pk;
                pk.x = pack2(acc[m][n][0] + bs[n], acc[m][n][1] + bs[n]);
                pk.y = pack2(acc[m][n][2] + bs[n], acc[m][n][3] + bs[n]);
                u16* dst = (u16*)Cv + ((size_t)(bbx * 8 + hh) * 64 + dd) * 1024 + ss;
                *(uint2*)dst = pk;
            } else {
#pragma unroll
                for (int j = 0; j < 4; ++j) {
                    int row = R0 + j;
                    float v = acc[m][n][j] + bs[n];
                    if (mode == 1) v *= QSCALE2;
                    ((u16*)Cv)[(size_t)row * 512 + col] = f2bf(v);
                }
            }
        }
    }
}

// ---------------------------------------------------------------------------
// rf64_k: RF GEMM, tile 128x64 (512 blocks -> 2/CU, 8 waves/CU), BK=32,
// 3-buffer counted vmcnt (3 loads/thread/stage -> waits 6/3/0). Fused
// transposed epilogue: out1 = rf, out0 = ff + conf*rf, with in-kernel
// confidence (from dbp) + outc write + invalid-loss atomics.
__global__ __launch_bounds__(256) void rf64_k(
    const u16* __restrict__ A, const u16* __restrict__ Bt,
    const float* __restrict__ bias, float* __restrict__ out0,
    const float* __restrict__ ffp, float* __restrict__ out1p,
    const float* __restrict__ dbpp, const void* __restrict__ maskp,
    const int* __restrict__ modep, float* __restrict__ outcp,
    float* __restrict__ scalp) {
    __shared__ u16 As[3][4096];   // 8 KB each
    __shared__ u16 Bs[3][2048];   // 4 KB each
    __shared__ float confL[128];
    int L = blockIdx.x;
    int W = (L & 7) * 64 + (L >> 3);          // XCD swizzle (512 % 8 == 0)
    int m0 = (W >> 3) * 128, n0 = (W & 7) * 64;
    int tid = threadIdx.x, w = tid >> 6, l = tid & 63;
    int lr = l & 15, g = l >> 4;
    int wr = w >> 1, wc = w & 1;
    int prm = g ^ ((lr >> 1) & 3);

    f32x4 acc[4][2] = {};

    // confidence for this block's 128 rows (before staging)
    if (tid < 128) {
        int row = m0 + tid;
        const float* dr = dbpp + (size_t)row * NH_;
        float s = 0;
#pragma unroll
        for (int h = 0; h < 8; ++h) s += dr[h];
        float cf = 1.0f - s * 0.125f;
        confL[tid] = cf;
        if ((W & 7) == 0) {
            outcp[row] = cf;
            int md = *modep;
            float invd = is_valid(maskp, md, row) ? 0.0f : 1.0f;
            float a = cf * invd, bsum = invd;
            for (int o = 32; o; o >>= 1) {
                a += __shfl_down(a, o);
                bsum += __shfl_down(bsum, o);
            }
            if ((tid & 63) == 0) {
                atomicAdd(&scalp[0], a);
                atomicAdd(&scalp[1], bsum);
            }
        }
    }

    auto stage = [&](int buf, int k0) {
#pragma unroll
        for (int j = 0; j < 2; ++j) {          // A: 512 granules
            int i = tid + 256 * j;
            int row = i >> 2, gg = (i & 3) ^ ((i >> 3) & 3);
            g2l16((char*)As[buf] + (size_t)i * 16,
                  A + (size_t)(m0 + row) * 512 + k0 + gg * 8);
        }
        {                                      // B: 256 granules
            int col = tid >> 2, gg = (tid & 3) ^ ((tid >> 3) & 3);
            g2l16((char*)Bs[buf] + (size_t)tid * 16,
                  Bt + (size_t)(n0 + col) * 512 + k0 + gg * 8);
        }
    };

    auto compute = [&](int bi) {
        const char* Ab = (const char*)As[bi];
        const char* Bb = (const char*)Bs[bi];
        short8 af[4], bf[2];
#pragma unroll
        for (int m = 0; m < 4; ++m)
            af[m] = *(const short8*)(Ab + ((wr * 64 + m * 16 + lr) * 4 + prm) * 16);
#pragma unroll
        for (int n = 0; n < 2; ++n)
            bf[n] = *(const short8*)(Bb + ((wc * 32 + n * 16 + lr) * 4 + prm) * 16);
        __builtin_amdgcn_s_setprio(1);
#pragma unroll
        for (int m = 0; m < 4; ++m)
#pragma unroll
            for (int n = 0; n < 2; ++n)
                acc[m][n] = __builtin_amdgcn_mfma_f32_16x16x32_bf16(
                    af[m], bf[n], acc[m][n], 0, 0, 0);
        __builtin_amdgcn_s_setprio(0);
    };

    stage(0, 0);
    stage(1, 32);
    for (int t = 0; t < 14; ++t) {
        stage((t + 2) % 3, (t + 2) * 32);
        GWAITBAR(6);
        compute(t % 3);
        __builtin_amdgcn_s_barrier();
    }
    GWAITBAR(3);
    compute(2);
    GWAITBAR(0);
    compute(0);

    float bs[2] = {bias[n0 + wc * 32 + lr], bias[n0 + wc * 32 + 16 + lr]};
#pragma unroll
    for (int m = 0; m < 4; ++m)
#pragma unroll
        for (int n = 0; n < 2; ++n) {
            int R0  = m0 + wr * 64 + m * 16 + 4 * g;
            int col = n0 + wc * 32 + n * 16 + lr;
            int bbx = R0 >> 10, t0p = R0 & 1023;
            size_t base = (size_t)bbx * C_ * T_ + (size_t)col * T_ + t0p;
            float4 rf;
            rf.x = acc[m][n][0] + bs[n]; rf.y = acc[m][n][1] + bs[n];
            rf.z = acc[m][n][2] + bs[n]; rf.w = acc[m][n][3] + bs[n];
            float4 ffv = *(const float4*)(ffp + base);
            float4 cfv = *(const float4*)&confL[R0 - m0];
            float4 o0v;
            o0v.x = ffv.x + cfv.x * rf.x; o0v.y = ffv.y + cfv.y * rf.y;
            o0v.z = ffv.z + cfv.z * rf.z; o0v.w = ffv.w + cfv.w * rf.w;
            *(float4*)(out1p + base) = rf;
            *(float4*)(out0 + base) = o0v;
        }
}

// ---------------------------------------------------------------------------
// Merged LayerNorms (E and SE). grid 16384: sel = blk>>13. (r11/r14-proven)
__global__ __launch_bounds__(256) void ln2_k(
    const u16* __restrict__ X0, const float* __restrict__ g0,
    const float* __restrict__ b0, u16* __restrict__ O0,
    const u16* __restrict__ X1, const float* __restrict__ g1,
    const float* __restrict__ b1, u16* __restrict__ O1) {
    int sel = blockIdx.x >> 13;
    int row = blockIdx.x & 8191;
    const u16* X = sel ? X1 : X0;
    const float* gw = sel ? g1 : g0;
    const float* bw = sel ? b1 : b0;
    u16* out = sel ? O1 : O0;
    int tid = threadIdx.x;
    const unsigned* xr = (const unsigned*)(X + (size_t)row * D_);
    unsigned u = xr[tid];
    float x0 = bf2f((u16)(u & 0xffff)), x1 = bf2f((u16)(u >> 16));
    float s = x0 + x1, sq = x0 * x0 + x1 * x1;
    __shared__ float rs[4], rq[4];
    for (int o = 32; o; o >>= 1) { s += __shfl_down(s, o); sq += __shfl_down(sq, o); }
    int wid = tid >> 6, lane = tid & 63;
    if (lane == 0) { rs[wid] = s; rq[wid] = sq; }
    __syncthreads();
    if (tid == 0) {
        float ts = 0, tq = 0;
        for (int w = 0; w < 4; ++w) { ts += rs[w]; tq += rq[w]; }
        rs[0] = ts; rq[0] = tq;
    }
    __syncthreads();
    float mean = rs[0] * (1.0f / D_);
    float var  = rq[0] * (1.0f / D_) - mean * mean;
    float r = rsqrtf(var + 1e-5f);
    float2 g2 = *(const float2*)(gw + 2 * tid);
    float2 b2 = *(const float2*)(bw + 2 * tid);
    float y0 = (x0 - mean) * r * g2.x + b2.x;
    float y1 = (x1 - mean) * r * g2.y + b2.y;
    ((unsigned*)(out + (size_t)row * D_))[tid] = pack2(y0, y1);
}

// ---------------------------------------------------------------------------
// head2_k: folded sigma + dustbin heads from E (H1) and PLH (H2), using
// TRANSPOSED weight layouts (dbwT[h][n], wdbfT[h][k]) so every weight load
// is coalesced (32 B lane-stride). One wave per row, 2048 blocks. (r14-proven)
__global__ __launch_bounds__(256) void head2_k(
    const u16* __restrict__ E, const u16* __restrict__ PLH,
    const float* __restrict__ sigw, const float* __restrict__ sigb,
    const float* __restrict__ wsig, const float* __restrict__ dbwT,
    const float* __restrict__ wdbfT, const float* __restrict__ dbb,
    const float* __restrict__ offs,
    float* __restrict__ sigma, float* __restrict__ dbo) {
    int wv = threadIdx.x >> 6, lane = threadIdx.x & 63;
    int row = blockIdx.x * 4 + wv;
    uint4 ue = *((const uint4*)(E + (size_t)row * 512) + lane);
    float Ev[8];
    Ev[0] = bf2f((u16)(ue.x & 0xffff)); Ev[1] = bf2f((u16)(ue.x >> 16));
    Ev[2] = bf2f((u16)(ue.y & 0xffff)); Ev[3] = bf2f((u16)(ue.y >> 16));
    Ev[4] = bf2f((u16)(ue.z & 0xffff)); Ev[5] = bf2f((u16)(ue.z >> 16));
    Ev[6] = bf2f((u16)(ue.w & 0xffff)); Ev[7] = bf2f((u16)(ue.w >> 16));
    uint4 up = *((const uint4*)(PLH + (size_t)row * 512) + lane);
    float plv[8];
    plv[0] = bf2f((u16)(up.x & 0xffff)); plv[1] = bf2f((u16)(up.x >> 16));
    plv[2] = bf2f((u16)(up.y & 0xffff)); plv[3] = bf2f((u16)(up.y >> 16));
    plv[4] = bf2f((u16)(up.z & 0xffff)); plv[5] = bf2f((u16)(up.z >> 16));
    plv[6] = bf2f((u16)(up.w & 0xffff)); plv[7] = bf2f((u16)(up.w >> 16));

    int n0 = lane * 8;
    float4 sw0 = *(const float4*)(sigw + n0);
    float4 sw1 = *(const float4*)(sigw + n0 + 4);
    float4 fw0 = *(const float4*)(wsig + n0);
    float4 fw1 = *(const float4*)(wsig + n0 + 4);
    float swv[8] = {sw0.x, sw0.y, sw0.z, sw0.w, sw1.x, sw1.y, sw1.z, sw1.w};
    float fwv[8] = {fw0.x, fw0.y, fw0.z, fw0.w, fw1.x, fw1.y, fw1.z, fw1.w};
    float sacc = 0;
#pragma unroll
    for (int i = 0; i < 8; ++i) sacc += Ev[i] * swv[i] + plv[i] * fwv[i];

    float d_[8];
#pragma unroll
    for (int h = 0; h < 8; ++h) {
        const float* ar = dbwT + h * 512 + n0;
        const float* br = wdbfT + h * 512 + n0;
        float4 a0v = *(const float4*)ar;
        float4 a1v = *(const float4*)(ar + 4);
        float4 b0v = *(const float4*)br;
        float4 b1v = *(const float4*)(br + 4);
        d_[h] = Ev[0] * a0v.x + Ev[1] * a0v.y + Ev[2] * a0v.z + Ev[3] * a0v.w +
                Ev[4] * a1v.x + Ev[5] * a1v.y + Ev[6] * a1v.z + Ev[7] * a1v.w +
                plv[0] * b0v.x + plv[1] * b0v.y + plv[2] * b0v.z + plv[3] * b0v.w +
                plv[4] * b1v.x + plv[5] * b1v.y + plv[6] * b1v.z + plv[7] * b1v.w;
    }
    for (int o = 1; o < 64; o <<= 1) {
        sacc += __shfl_xor(sacc, o);
#pragma unroll
        for (int h = 0; h < 8; ++h) d_[h] += __shfl_xor(d_[h], o);
    }
    if (lane == 0) {
        float z = sacc + sigb[0] + offs[0];
        sigma[row] = 0.03f + 0.32f / (1.0f + __expf(-z));
        float* dd = dbo + (size_t)row * NH_;
#pragma unroll
        for (int h = 0; h < 8; ++h) dd[h] = d_[h] + dbb[h] + offs[1 + h];
    }
}

// ---------------------------------------------------------------------------
// Staged MFMA flash attention, KVBLK=64, exp2 softmax, 512-thread blocks.
// Issue-then-counted-wait staging (vmcnt(2)); -m_st folded into AbaseM;
// cross-lane max only in rescale branch; l-sum via ones-row MFMA; max3 tree.
// P stays in registers via bit-permuted K staging. 44 KB LDS.
__global__ __launch_bounds__(512) void attn_k(
    const u16* __restrict__ Q, const u16* __restrict__ K,
    const u16* __restrict__ Vt, const float* __restrict__ sig,
    const float* __restrict__ dbl, const float* __restrict__ bev,
    const float* __restrict__ sxy, const void* __restrict__ mask,
    const int* __restrict__ mode, u16* __restrict__ OUT,
    float* __restrict__ dbp) {
    int L = blockIdx.x;
    int W = (L & 7) * 64 + (L >> 3);   // XCD swizzle
    int b = W >> 6, h = (W >> 3) & 7, tblk = W & 7;
    int tid = threadIdx.x, w = tid >> 6, l = tid & 63;
    int lr = l & 15, g = l >> 4;
    int p8 = lr & 7;                   // LDS read granule permutation

    __shared__ u16 Kbuf[2][4096];      // 8 KB each
    __shared__ u16 Vbuf[2][4096];      // 8 KB each
    __shared__ float2 SXY[1024];       // (-2x, -2y)
    __shared__ float  SZ[1024];        // x^2+y^2

    const float2* xp = (const float2*)(sxy + (size_t)b * S_ * 2);
#pragma unroll
    for (int j = 0; j < 2; ++j) {
        int idx = tid + 512 * j;
        float2 v = xp[idx];
        SXY[idx] = make_float2(-2.0f * v.x, -2.0f * v.y);
        SZ[idx] = v.x * v.x + v.y * v.y;
    }

    int trow = b * T_ + tblk * 128 + w * 16 + lr;
    float s_ = sig[trow];
    float bx = bev[(size_t)trow * 2], by = bev[(size_t)trow * 2 + 1];
    float dbv2 = dbl[(size_t)trow * NH_ + h] * INVLN2;
    int md = *mode;
    bool vld = is_valid(mask, md, trow) != 0;
    float grow  = vld ? (-11.5415603271117f / fmaxf(s_ * s_, 1e-6f)) : 0.0f;
    float Abase = vld ? grow * (bx * bx + by * by) : -10000.0f;
    float AbaseM = Abase - dbv2;       // Abase - m_st, maintained across chunks
    float mshift = 0.0f;               // dbv2 - m_st

    const u16* qp = Q + (size_t)trow * 512 + h * 64 + g * 8;
    short8 q0 = *(const short8*)qp;
    short8 q1 = *(const short8*)(qp + 32);
    if (!vld) { q0 = short8{}; q1 = short8{}; }

    short8 ones;
#pragma unroll
    for (int e = 0; e < 8; ++e) ones[e] = (short)0x3F80;   // bf16 1.0

    const u16* Kp = K + (size_t)b * S_ * 512 + h * 64;
    const u16* Vp = Vt + (size_t)(b * 8 + h) * 64 * 1024;

    // staging indices: slot row = tid>>3, permuted granule
    int srow = tid >> 3;                           // 0..63
    int gprm = (tid & 7) ^ (srow & 7);
    // K source row via sigma bit-permutation of the slot row
    int sK = ((srow >> 5) & 1) * 32 + ((srow >> 2) & 3) * 8 +
             ((srow >> 4) & 1) * 4 + (srow & 3);

    auto stageKV = [&](int buf, int s0) {
        g2l16((char*)Kbuf[buf] + (size_t)tid * 16,
              Kp + (size_t)(s0 + sK) * 512 + gprm * 8);
        g2l16((char*)Vbuf[buf] + (size_t)tid * 16,
              Vp + (size_t)srow * 1024 + s0 + gprm * 8);
    };

    f32x4 o0 = {}, o1 = {}, o2 = {}, o3 = {};
    f32x4 o4 = {1.0f, 1.0f, 1.0f, 1.0f};   // l-accumulator (dustbin term = 1)

    stageKV(0, 0);
    int cur = 0;
    for (int c = 0; c < 16; ++c) {
        int s0c = c * 64;
        if (c < 15) {
            stageKV(cur ^ 1, s0c + 64);
            GWAITBAR(2);               // chunk c landed; next chunk in flight
        } else {
            GWAITBAR(0);
        }

        const char* Kc = (const char*)Kbuf[cur];
        const char* Vc = (const char*)Vbuf[cur];

        f32x4 p[4];
        f32x4 z4 = {};
        __builtin_amdgcn_s_setprio(1);
#pragma unroll
        for (int sub = 0; sub < 4; ++sub) {
            int krow = sub * 16 + lr;
            short8 kf0 = *(const short8*)(Kc + (krow * 8 + (g ^ p8)) * 16);
            short8 kf1 = *(const short8*)(Kc + (krow * 8 + ((4 + g) ^ p8)) * 16);
            p[sub] = __builtin_amdgcn_mfma_f32_16x16x32_bf16(kf0, q0, z4, 0, 0, 0);
            p[sub] = __builtin_amdgcn_mfma_f32_16x16x32_bf16(kf1, q1, p[sub], 0, 0, 0);
        }
        __builtin_amdgcn_s_setprio(0);

        // logits, already max-shifted: lg = raw - m_st
        float lg[16];
#pragma unroll
        for (int sub = 0; sub < 4; ++sub) {
            int sl = s0c + ((sub & 2) << 4) + 8 * g + ((sub & 1) << 2);
            float4 xy01 = *(const float4*)&SXY[sl];
            float4 xy23 = *(const float4*)&SXY[sl + 2];
            float4 zz   = *(const float4*)&SZ[sl];
            float X[4] = {xy01.x, xy01.z, xy23.x, xy23.z};
            float Y[4] = {xy01.y, xy01.w, xy23.y, xy23.w};
            float Z[4] = {zz.x, zz.y, zz.z, zz.w};
#pragma unroll
            for (int i2 = 0; i2 < 4; ++i2) {
                float wg = fmaf(bx, X[i2], fmaf(by, Y[i2], Z[i2]));
                lg[sub * 4 + i2] = fmaf(grow, wg, p[sub][i2] + AbaseM);
            }
        }
        // local max via max3 tree
        float c0 = max3f(lg[0], lg[1], lg[2]);
        float c1 = max3f(lg[3], lg[4], lg[5]);
        float c2 = max3f(lg[6], lg[7], lg[8]);
        float c3 = max3f(lg[9], lg[10], lg[11]);
        float c4 = max3f(lg[12], lg[13], lg[14]);
        float cl = fmaxf(max3f(c0, c1, c2), max3f(c3, c4, lg[15]));

        if (!__all(cl <= 11.5f)) {            // rare: true max exceeds m_st+THR
            cl = fmaxf(cl, __shfl_xor(cl, 16));
            cl = fmaxf(cl, __shfl_xor(cl, 32));
            float dm = fmaxf(cl, 0.0f);       // m_new - m_st
            float scl = fexp2(-dm);
            o0 *= scl; o1 *= scl; o2 *= scl; o3 *= scl; o4 *= scl;
            AbaseM -= dm;
            mshift -= dm;
#pragma unroll
            for (int r = 0; r < 16; ++r) lg[r] -= dm;
        }
        float pe[16];
#pragma unroll
        for (int r = 0; r < 16; ++r) pe[r] = fexp2(lg[r]);

        union { uint4 u; short8 s8; } pf0, pf1;
        pf0.u.x = pack2(pe[0], pe[1]);  pf0.u.y = pack2(pe[2], pe[3]);
        pf0.u.z = pack2(pe[4], pe[5]);  pf0.u.w = pack2(pe[6], pe[7]);
        pf1.u.x = pack2(pe[8], pe[9]);  pf1.u.y = pack2(pe[10], pe[11]);
        pf1.u.z = pack2(pe[12], pe[13]); pf1.u.w = pack2(pe[14], pe[15]);

        __builtin_amdgcn_s_setprio(1);
        short8 vf;
#pragma unroll
        for (int dt = 0; dt < 4; ++dt) {
            int vrow = dt * 16 + lr;
            f32x4* oo = (dt == 0) ? &o0 : (dt == 1) ? &o1 : (dt == 2) ? &o2 : &o3;
            vf = *(const short8*)(Vc + (vrow * 8 + (g ^ p8)) * 16);
            *oo = __builtin_amdgcn_mfma_f32_16x16x32_bf16(vf, pf0.s8, *oo, 0, 0, 0);
            vf = *(const short8*)(Vc + (vrow * 8 + ((4 + g) ^ p8)) * 16);
            *oo = __builtin_amdgcn_mfma_f32_16x16x32_bf16(vf, pf1.s8, *oo, 0, 0, 0);
        }
        // l-sum on the matrix pipe: ones-row x P
        o4 = __builtin_amdgcn_mfma_f32_16x16x32_bf16(ones, pf0.s8, o4, 0, 0, 0);
        o4 = __builtin_amdgcn_mfma_f32_16x16x32_bf16(ones, pf1.s8, o4, 0, 0, 0);
        __builtin_amdgcn_s_setprio(0);

        __builtin_amdgcn_s_barrier();   // all reads of buf cur done before reuse
        cur ^= 1;
    }

    float inv = 1.0f / o4[0];
    u16* ob = OUT + (size_t)trow * 512 + h * 64;
    {
        uint2 pk;
        pk.x = pack2(o0[0] * inv, o0[1] * inv); pk.y = pack2(o0[2] * inv, o0[3] * inv);
        *(uint2*)(ob + 0 * 16 + 4 * g) = pk;
        pk.x = pack2(o1[0] * inv, o1[1] * inv); pk.y = pack2(o1[2] * inv, o1[3] * inv);
        *(uint2*)(ob + 1 * 16 + 4 * g) = pk;
        pk.x = pack2(o2[0] * inv, o2[1] * inv); pk.y = pack2(o2[2] * inv, o2[3] * inv);
        *(uint2*)(ob + 2 * 16 + 4 * g) = pk;
        pk.x = pack2(o3[0] * inv, o3[1] * inv); pk.y = pack2(o3[2] * inv, o3[3] * inv);
        *(uint2*)(ob + 3 * 16 + 4 * g) = pk;
    }
    if (g == 0) dbp[(size_t)trow * NH_ + h] = fexp2(mshift) * inv;
}

__global__ void loss_k(const float* __restrict__ scal, float* __restrict__ out) {
    out[0] = scal[0] / fmaxf(scal[1], 1.0f) * 0.05f;
}

// ---------------------------------------------------------------------------
extern "C" void kernel_launch(void* const* d_in, const int* in_sizes, int n_in,
                              void* d_out, int out_size, void* d_ws, size_t ws_size,
                              hipStream_t stream) {
    const float* front_feat = (const float*)d_in[0];
    const float* sat_tokens = (const float*)d_in[1];
    const float* sat_xy     = (const float*)d_in[2];
    const float* bev_xy     = (const float*)d_in[3];
    const void*  mask       = d_in[4];
    const float* plucker    = (const float*)d_in[5];
    const float* fa_w = (const float*)d_in[6];
    const float* fa_b = (const float*)d_in[7];
    const float* fa_g = (const float*)d_in[8];
    const float* fa_lb = (const float*)d_in[9];
    const float* sa_w = (const float*)d_in[10];
    const float* sa_b = (const float*)d_in[11];
    const float* sa_g = (const float*)d_in[12];
    const float* sa_lb = (const float*)d_in[13];
    const float* q_w = (const float*)d_in[14];
    const float* q_b = (const float*)d_in[15];
    const float* k_w = (const float*)d_in[16];
    const float* k_b = (const float*)d_in[17];
    const float* v_w = (const float*)d_in[18];
    const float* v_b = (const float*)d_in[19];
    const float* pl_w1 = (const float*)d_in[20];
    const float* pl_b1 = (const float*)d_in[21];
    const float* pl_w2 = (const float*)d_in[22];
    const float* pl_b2 = (const float*)d_in[23];
    const float* sig_w = (const float*)d_in[24];
    const float* sig_b = (const float*)d_in[25];
    const float* db_w = (const float*)d_in[26];
    const float* db_b = (const float*)d_in[27];
    const float* out_w = (const float*)d_in[28];
    const float* out_b = (const float*)d_in[29];

    char* w8 = (char*)d_ws;
    u16* H0 = (u16*)(w8);                        // 8 MB bf16 slots
    u16* H1 = (u16*)(w8 + 8388608ull * 1);
    u16* H2 = (u16*)(w8 + 8388608ull * 2);
    u16* H3 = (u16*)(w8 + 8388608ull * 3);
    u16* H4 = (u16*)(w8 + 8388608ull * 4);
    u16* H5 = (u16*)(w8 + 8388608ull * 5);
    u16* H6 = (u16*)(w8 + 8388608ull * 6);
    u16* WT = (u16*)(w8 + 8388608ull * 7);       // 6 x 0.5 MB
    char* sm = w8 + 8388608ull * 7 + 3670016ull;
    float* w_sigma = (float*)sm;
    float* w_db    = w_sigma + BT_;
    float* w_dbp   = w_db + (size_t)BT_ * NH_;
    float* w_scal  = w_dbp + (size_t)BT_ * NH_;
    int*   w_mode  = (int*)(w_scal + 2);
    float* w_wsig  = w_scal + 4;                 // 512
    float* w_wdbfT = w_wsig + 512;               // 4096
    float* w_offs  = w_wdbfT + 4096;             // 9 (pad to 16)
    float* w_dbwT  = w_offs + 16;                // 4096

    u16* Wfa = WT;                 u16* Wq  = WT + 262144ull * 1;
    u16* Wsa = WT + 262144ull * 2; u16* Wk  = WT + 262144ull * 3;
    u16* Wv  = WT + 262144ull * 4; u16* Wo  = WT + 262144ull * 5;

    float* out0 = (float*)d_out;
    float* out1 = out0 + (size_t)B_ * C_ * T_;
    float* outc = out1 + (size_t)B_ * C_ * T_;
    float* outl = outc + (size_t)B_ * T_;

    dim3 blk(256);

    // 1. prep: mode + 6 weight transposes + front transpose (H0) + sat (H5)
    //    + plucker hidden (H2) + head weight folds (transposed layouts)
    prep_k<<<dim3(9749), blk, 0, stream>>>(
        front_feat, sat_tokens, plucker,
        fa_w, q_w, sa_w, k_w, v_w, out_w, WT,
        H0, H5, pl_w1, pl_b1, H2,
        (const unsigned*)mask, w_mode, w_scal,
        pl_w2, sig_w, db_w, pl_b2, w_wsig, w_wdbfT, w_offs, w_dbwT);
    // 2. E_pre (H0@Wfa -> H6) and SAT_pre (H5@Wsa -> H4), 512 blocks
    gmm_k<<<dim3(512), blk, 0, stream>>>(
        H0, H5, nullptr,
        Wfa, Wsa, nullptr,
        fa_b, sa_b, nullptr,
        H6, H4, nullptr,
        0, 0, 0);
    // 3. LN(E_pre)->H1, LN(SAT_pre)->H3
    ln2_k<<<dim3(16384), blk, 0, stream>>>(H6, fa_g, fa_lb, H1,
                                           H4, sa_g, sa_lb, H3);
    // 4. sigma/dustbin heads from E (H1) + PLH (H2), folded+coalesced
    head2_k<<<dim3(2048), blk, 0, stream>>>(
        H1, H2, sig_w, sig_b, w_wsig, w_dbwT, w_wdbfT, db_b, w_offs,
        w_sigma, w_db);
    // 5. Q (H1->H5, scale), K (H3->H0), Vt (H3->H4 scatter), 768 blocks
    gmm_k<<<dim3(768), blk, 0, stream>>>(
        H1, H3, H3,
        Wq, Wk, Wv,
        q_b, k_b, v_b,
        H5, H0, H4,
        1, 0, 3);
    // 6. attention: Q=H5, K=H0, Vt=H4 -> OUT=H2
    attn_k<<<dim3(512), dim3(512), 0, stream>>>(
        H5, H0, H4, w_sigma, w_db, bev_xy, sat_xy, mask, w_mode, H2, w_dbp);
    // 7. RF = H2 @ Wo (128x64 tiles, 512 blocks), fused transposed epilogue
    //    + in-kernel confidence/loss
    rf64_k<<<dim3(512), blk, 0, stream>>>(
        H2, Wo, out_b, out0, front_feat, out1,
        w_dbp, mask, w_mode, outc, w_scal);
    // 8. loss scalar
    loss_k<<<1, 1, 0, stream>>>(w_scal, outl);
}

// Round 17
// 140.749 us; speedup vs baseline: 1.1347x; 1.0699x over previous
//
#include <hip/hip_runtime.h>

typedef unsigned short u16;
typedef __attribute__((ext_vector_type(8))) short short8;   // 8 bf16 = 4 VGPR
typedef __attribute__((ext_vector_type(4))) float f32x4;    // MFMA acc

// Problem constants
constexpr int B_  = 8;
constexpr int C_  = 512;
constexpr int T_  = 1024;   // H*W
constexpr int S_  = 1024;
constexpr int D_  = 512;
constexpr int NH_ = 8;
constexpr int BT_ = B_ * T_;   // 8192
constexpr float INVLN2 = 1.44269504088896340736f;
constexpr float QSCALE2 = 0.0125f * INVLN2;   // COMPAT/sqrt(HD) / ln2

// single-instruction f32x2 -> packed bf16x2 (RNE)
__device__ __forceinline__ unsigned pack2(float lo, float hi) {
    unsigned r;
    asm("v_cvt_pk_bf16_f32 %0, %1, %2" : "=v"(r) : "v"(lo), "v"(hi));
    return r;
}
__device__ __forceinline__ u16 f2bf(float x) {
    return (u16)pack2(x, x);
}
__device__ __forceinline__ float bf2f(u16 h) {
    union { unsigned u; float f; } v; v.u = ((unsigned)h) << 16;
    return v.f;
}
__device__ __forceinline__ float fexp2(float x) {   // 2^x
    float r;
    asm("v_exp_f32 %0, %1" : "=v"(r) : "v"(x));
    return r;
}
__device__ __forceinline__ float max3f(float a, float b, float c) {
    float r;
    asm("v_max3_f32 %0, %1, %2, %3" : "=v"(r) : "v"(a), "v"(b), "v"(c));
    return r;
}

// counted-wait + raw barrier (T4): leaves N vector-loads in flight.
#define GWAITBAR(N) do { \
    asm volatile("s_waitcnt vmcnt(" #N ") lgkmcnt(0)" ::: "memory"); \
    __builtin_amdgcn_sched_barrier(0); \
    __builtin_amdgcn_s_barrier(); \
    __builtin_amdgcn_sched_barrier(0); } while (0)

// async global->LDS 16B
typedef __attribute__((address_space(3))) unsigned int lds_u32;
typedef const __attribute__((address_space(1))) unsigned int glob_u32;
__device__ __forceinline__ void g2l16(void* l, const void* g) {
    __builtin_amdgcn_global_load_lds((glob_u32*)g, (lds_u32*)l, 16, 0, 0);
}

// ---------------------------------------------------------------------------
// mask mode detect (int32 / f32 / bytes)
__device__ __forceinline__ int is_valid(const void* mask, int mode, int idx) {
    if (mode == 0) return ((const int*)mask)[idx] != 0;
    if (mode == 1) return ((const float*)mask)[idx] != 0.0f;
    return ((const unsigned char*)mask)[idx] != 0;
}

// ---------------------------------------------------------------------------
// prep_k: mode-detect + 6x weight transpose/convert + front transpose
// + sat f32->bf16 + plucker MLP hidden + head weight folds.
// ROUND 17: folds parallelized — one block per k (512 blocks) instead of a
// 20-block serial tail; each thread takes 2 n-values, 9-value reduction.
__global__ __launch_bounds__(256) void prep_k(
    const float* __restrict__ ff, const float* __restrict__ sat,
    const float* __restrict__ pl,
    const float* a0, const float* a1, const float* a2, const float* a3,
    const float* a4, const float* a5, u16* __restrict__ WT,
    u16* __restrict__ ffb, u16* __restrict__ satb,
    const float* __restrict__ plw1, const float* __restrict__ plb1,
    u16* __restrict__ plh,
    const unsigned* __restrict__ maskw, int* __restrict__ mode,
    float* __restrict__ scal,
    const float* __restrict__ plw2, const float* __restrict__ sigw,
    const float* __restrict__ dbw, const float* __restrict__ plb2,
    float* __restrict__ wsig, float* __restrict__ wdbfT,
    float* __restrict__ offs, float* __restrict__ dbwT) {
    __shared__ float tile[32][33];
    int blk = blockIdx.x, tid = threadIdx.x;
    if (blk < 4096) {                       // front_feat (B,C,T) -> (B*T,C) bf16
        int t0 = (blk & 31) * 32, c0 = ((blk >> 5) & 15) * 32, b = blk >> 9;
        int tx = tid & 31, ty = tid >> 5;
        const float* ip = ff + (size_t)b * C_ * T_;
        for (int i = ty; i < 32; i += 8)
            tile[i][tx] = ip[(size_t)(c0 + i) * T_ + t0 + tx];
        __syncthreads();
        u16* op = ffb + (size_t)b * T_ * C_;
        for (int i = ty; i < 32; i += 8)
            op[(size_t)(t0 + i) * C_ + c0 + tx] = f2bf(tile[tx][i]);
    } else if (blk < 5632) {                // weight W[k][n] -> Wt[n][k] bf16
        int idx = blk - 4096;
        const float* srcs[6] = {a0, a1, a2, a3, a4, a5};
        int z = idx >> 8;
        const float* src = srcs[z];
        u16* d = WT + (size_t)z * 512 * 512;
        int k0 = (idx & 15) * 32, n0 = ((idx >> 4) & 15) * 32;
        int tx = tid & 31, ty = tid >> 5;
        for (int i = ty; i < 32; i += 8)
            tile[i][tx] = src[(size_t)(k0 + i) * 512 + n0 + tx];
        __syncthreads();
        for (int i = ty; i < 32; i += 8)
            d[(size_t)(n0 + i) * 512 + k0 + tx] = f2bf(tile[tx][i]);
    } else if (blk < 7680) {                // sat f32 -> bf16 (x8 per thread)
        int i = (blk - 5632) * 256 + tid;
        const float4* p = (const float4*)(sat + (size_t)i * 8);
        float4 a = p[0], b = p[1];
        uint4 o;
        o.x = pack2(a.x, a.y); o.y = pack2(a.z, a.w);
        o.z = pack2(b.x, b.y); o.w = pack2(b.z, b.w);
        *(uint4*)(satb + (size_t)i * 8) = o;
    } else if (blk < 9728) {                // plucker hidden: silu MLP (K=6)
        int m = (blk - 7680) * 4 + (tid >> 6);
        int lane = tid & 63;
        float p6[6];
#pragma unroll
        for (int j = 0; j < 6; ++j) p6[j] = pl[(size_t)m * 6 + j];
        int n0 = lane * 8;
        float acc[8];
#pragma unroll
        for (int e = 0; e < 8; ++e) acc[e] = plb1[n0 + e];
#pragma unroll
        for (int j = 0; j < 6; ++j) {
            float4 wv0 = *(const float4*)(plw1 + j * D_ + n0);
            float4 wv1 = *(const float4*)(plw1 + j * D_ + n0 + 4);
            acc[0] += p6[j] * wv0.x; acc[1] += p6[j] * wv0.y;
            acc[2] += p6[j] * wv0.z; acc[3] += p6[j] * wv0.w;
            acc[4] += p6[j] * wv1.x; acc[5] += p6[j] * wv1.y;
            acc[6] += p6[j] * wv1.z; acc[7] += p6[j] * wv1.w;
        }
        uint4 o;
        float s0 = acc[0] / (1.0f + __expf(-acc[0]));
        float s1 = acc[1] / (1.0f + __expf(-acc[1]));
        float s2 = acc[2] / (1.0f + __expf(-acc[2]));
        float s3 = acc[3] / (1.0f + __expf(-acc[3]));
        float s4 = acc[4] / (1.0f + __expf(-acc[4]));
        float s5 = acc[5] / (1.0f + __expf(-acc[5]));
        float s6 = acc[6] / (1.0f + __expf(-acc[6]));
        float s7 = acc[7] / (1.0f + __expf(-acc[7]));
        o.x = pack2(s0, s1); o.y = pack2(s2, s3);
        o.z = pack2(s4, s5); o.w = pack2(s6, s7);
        *(uint4*)(plh + (size_t)m * D_ + n0) = o;
    } else if (blk == 9728) {               // mode detect + zero accumulators
        __shared__ int bad_i, bad_f;
        if (tid == 0) { bad_i = 0; bad_f = 0; }
        __syncthreads();
        for (int i = tid; i < 2048; i += 256) {
            unsigned v = maskw[i];
            if (v > 1u) bad_i = 1;
            if (v != 0u && v != 0x3f800000u) bad_f = 1;
        }
        __syncthreads();
        if (tid == 0) {
            *mode = (!bad_i) ? 0 : ((!bad_f) ? 1 : 2);
            scal[0] = 0.0f; scal[1] = 0.0f;
        }
    } else if (blk < 10241) {               // per-k fold: wsig[k], wdbfT[.][k]
        int k = blk - 9729;
        float av0 = plw2[(size_t)k * 512 + tid];
        float av1 = plw2[(size_t)k * 512 + tid + 256];
        float ps = av0 * sigw[tid] + av1 * sigw[tid + 256];
        float4 d0a = *(const float4*)(dbw + tid * 8);
        float4 d0b = *(const float4*)(dbw + tid * 8 + 4);
        float4 d1a = *(const float4*)(dbw + (tid + 256) * 8);
        float4 d1b = *(const float4*)(dbw + (tid + 256) * 8 + 4);
        float ph[8];
        ph[0] = av0 * d0a.x + av1 * d1a.x; ph[1] = av0 * d0a.y + av1 * d1a.y;
        ph[2] = av0 * d0a.z + av1 * d1a.z; ph[3] = av0 * d0a.w + av1 * d1a.w;
        ph[4] = av0 * d0b.x + av1 * d1b.x; ph[5] = av0 * d0b.y + av1 * d1b.y;
        ph[6] = av0 * d0b.z + av1 * d1b.z; ph[7] = av0 * d0b.w + av1 * d1b.w;
        for (int o = 32; o; o >>= 1) {
            ps += __shfl_down(ps, o);
#pragma unroll
            for (int h = 0; h < 8; ++h) ph[h] += __shfl_down(ph[h], o);
        }
        __shared__ float redk[4][9];
        int wv = tid >> 6, lane = tid & 63;
        if (lane == 0) {
            redk[wv][0] = ps;
#pragma unroll
            for (int h = 0; h < 8; ++h) redk[wv][1 + h] = ph[h];
        }
        __syncthreads();
        if (tid == 0) {
            float t0 = redk[0][0] + redk[1][0] + redk[2][0] + redk[3][0];
            wsig[k] = t0;
#pragma unroll
            for (int h = 0; h < 8; ++h) {
                float th = redk[0][1 + h] + redk[1][1 + h] +
                           redk[2][1 + h] + redk[3][1 + h];
                wdbfT[h * 512 + k] = th;
            }
        }
    } else if (blk == 10241) {              // offs: pl_b2 dotted with heads
        float p = plb2[tid] * sigw[tid] + plb2[tid + 256] * sigw[tid + 256];
        float ph[8];
#pragma unroll
        for (int h = 0; h < 8; ++h)
            ph[h] = plb2[tid] * dbw[tid * 8 + h] +
                    plb2[tid + 256] * dbw[(tid + 256) * 8 + h];
        for (int o = 32; o; o >>= 1) {
            p += __shfl_down(p, o);
#pragma unroll
            for (int h = 0; h < 8; ++h) ph[h] += __shfl_down(ph[h], o);
        }
        __shared__ float red[4][9];
        int wv = tid >> 6, lane = tid & 63;
        if (lane == 0) {
            red[wv][0] = p;
#pragma unroll
            for (int h = 0; h < 8; ++h) red[wv][1 + h] = ph[h];
        }
        __syncthreads();
        if (tid == 0) {
            for (int j = 0; j < 9; ++j) {
                float t = 0;
                for (int v2 = 0; v2 < 4; ++v2) t += red[v2][j];
                offs[j] = t;
            }
        }
    } else {                                // dbwT[h][n] = dbw[n][h]
        for (int i = tid; i < 4096; i += 256) {
            int h = i >> 9, n = i & 511;
            dbwT[h * 512 + n] = dbw[n * 8 + h];
        }
    }
}

// ---------------------------------------------------------------------------
// Generic multi-job bf16 MFMA GEMM. Tile 128x128, 4 waves (each 64x64),
// BK=32, 16 MFMA/wave/step. 3-buffer depth-2 prefetch with counted vmcnt(8).
// Modes: 0 bf16 plain; 1 bf16*QSCALE2; 3 Vt bf16 transposed scatter.
__global__ __launch_bounds__(256) void gmm_k(
    const u16* __restrict__ A0, const u16* __restrict__ A1,
    const u16* __restrict__ A2,
    const u16* __restrict__ Bt0, const u16* __restrict__ Bt1,
    const u16* __restrict__ Bt2,
    const float* __restrict__ bb0, const float* __restrict__ bb1,
    const float* __restrict__ bb2,
    void* __restrict__ C0v, void* __restrict__ C1v, void* __restrict__ C2v,
    int md0, int md1, int md2) {
    __shared__ u16 As[3][4096];   // 8 KB each
    __shared__ u16 Bs[3][4096];   // 8 KB each
    int jid = blockIdx.x >> 8;
    int L = blockIdx.x & 255;
    const u16* A    = (jid == 0) ? A0 : (jid == 1) ? A1 : A2;
    const u16* Bt   = (jid == 0) ? Bt0 : (jid == 1) ? Bt1 : Bt2;
    const float* bias = (jid == 0) ? bb0 : (jid == 1) ? bb1 : bb2;
    void* Cv        = (jid == 0) ? C0v : (jid == 1) ? C1v : C2v;
    int mode        = (jid == 0) ? md0 : (jid == 1) ? md1 : md2;

    int tid = threadIdx.x, w = tid >> 6, l = tid & 63;
    int lr = l & 15, g = l >> 4;
    int W = (L & 7) * 32 + (L >> 3);          // XCD swizzle (256 % 8 == 0)
    int m0 = (W >> 2) * 128, n0 = (W & 3) * 128;
    int wr = w >> 1, wc = w & 1;
    int prm = g ^ ((lr >> 1) & 3);            // LDS read granule permutation

    f32x4 acc[4][4] = {};

    auto stage = [&](int buf, int k0) {
#pragma unroll
        for (int j = 0; j < 2; ++j) {          // A: 512 granules
            int i = tid + 256 * j;
            int row = i >> 2, gg = (i & 3) ^ ((i >> 3) & 3);
            g2l16((char*)As[buf] + (size_t)i * 16,
                  A + (size_t)(m0 + row) * 512 + k0 + gg * 8);
        }
#pragma unroll
        for (int j = 0; j < 2; ++j) {          // B: 512 granules
            int i = tid + 256 * j;
            int col = i >> 2, gg = (i & 3) ^ ((i >> 3) & 3);
            g2l16((char*)Bs[buf] + (size_t)i * 16,
                  Bt + (size_t)(n0 + col) * 512 + k0 + gg * 8);
        }
    };

    auto compute = [&](int bi) {
        const char* Ab = (const char*)As[bi];
        const char* Bb = (const char*)Bs[bi];
        short8 af[4], bf[4];
#pragma unroll
        for (int m = 0; m < 4; ++m)
            af[m] = *(const short8*)(Ab + ((wr * 64 + m * 16 + lr) * 4 + prm) * 16);
#pragma unroll
        for (int n = 0; n < 4; ++n)
            bf[n] = *(const short8*)(Bb + ((wc * 64 + n * 16 + lr) * 4 + prm) * 16);
        __builtin_amdgcn_s_setprio(1);
#pragma unroll
        for (int m = 0; m < 4; ++m)
#pragma unroll
            for (int n = 0; n < 4; ++n)
                acc[m][n] = __builtin_amdgcn_mfma_f32_16x16x32_bf16(
                    af[m], bf[n], acc[m][n], 0, 0, 0);
        __builtin_amdgcn_s_setprio(0);
    };

    stage(0, 0);
    stage(1, 32);
    for (int t = 0; t < 14; ++t) {
        stage((t + 2) % 3, (t + 2) * 32);
        GWAITBAR(8);
        compute(t % 3);
        __builtin_amdgcn_s_barrier();
    }
    GWAITBAR(4);
    compute(2);
    GWAITBAR(0);
    compute(0);

    float bs[4];
#pragma unroll
    for (int n = 0; n < 4; ++n) bs[n] = bias[n0 + wc * 64 + n * 16 + lr];

#pragma unroll
    for (int m = 0; m < 4; ++m) {
#pragma unroll
        for (int n = 0; n < 4; ++n) {
            int R0  = m0 + wr * 64 + m * 16 + 4 * g;
            int col = n0 + wc * 64 + n * 16 + lr;
            if (mode == 3) {                   // Vt transposed scatter
                int bbx = R0 >> 10, ss = R0 & 1023, hh = col >> 6, dd = col & 63;
                uint2 pk;
                pk.x = pack2(acc[m][n][0] + bs[n], acc[m][n][1] + bs[n]);
                pk.y = pack2(acc[m][n][2] + bs[n], acc[m][n][3] + bs[n]);
                u16* dst = (u16*)Cv + ((size_t)(bbx * 8 + hh) * 64 + dd) * 1024 + ss;
                *(uint2*)dst = pk;
            } else {
#pragma unroll
                for (int j = 0; j < 4; ++j) {
                    int row = R0 + j;
                    float v = acc[m][n][j] + bs[n];
                    if (mode == 1) v *= QSCALE2;
                    ((u16*)Cv)[(size_t)row * 512 + col] = f2bf(v);
                }
            }
        }
    }
}

// ---------------------------------------------------------------------------
// rf64_k: RF GEMM, tile 128x64 (512 blocks -> 2/CU, 8 waves/CU), BK=32,
// 3-buffer counted vmcnt (3 loads/thread/stage -> waits 6/3/0). Fused
// transposed epilogue: out1 = rf, out0 = ff + conf*rf, with in-kernel
// confidence (from dbp) + outc write + invalid-loss atomics.
__global__ __launch_bounds__(256) void rf64_k(
    const u16* __restrict__ A, const u16* __restrict__ Bt,
    const float* __restrict__ bias, float* __restrict__ out0,
    const float* __restrict__ ffp, float* __restrict__ out1p,
    const float* __restrict__ dbpp, const void* __restrict__ maskp,
    const int* __restrict__ modep, float* __restrict__ outcp,
    float* __restrict__ scalp) {
    __shared__ u16 As[3][4096];   // 8 KB each
    __shared__ u16 Bs[3][2048];   // 4 KB each
    __shared__ float confL[128];
    int L = blockIdx.x;
    int W = (L & 7) * 64 + (L >> 3);          // XCD swizzle (512 % 8 == 0)
    int m0 = (W >> 3) * 128, n0 = (W & 7) * 64;
    int tid = threadIdx.x, w = tid >> 6, l = tid & 63;
    int lr = l & 15, g = l >> 4;
    int wr = w >> 1, wc = w & 1;
    int prm = g ^ ((lr >> 1) & 3);

    f32x4 acc[4][2] = {};

    // confidence for this block's 128 rows (before staging)
    if (tid < 128) {
        int row = m0 + tid;
        const float* dr = dbpp + (size_t)row * NH_;
        float s = 0;
#pragma unroll
        for (int h = 0; h < 8; ++h) s += dr[h];
        float cf = 1.0f - s * 0.125f;
        confL[tid] = cf;
        if ((W & 7) == 0) {
            outcp[row] = cf;
            int md = *modep;
            float invd = is_valid(maskp, md, row) ? 0.0f : 1.0f;
            float a = cf * invd, bsum = invd;
            for (int o = 32; o; o >>= 1) {
                a += __shfl_down(a, o);
                bsum += __shfl_down(bsum, o);
            }
            if ((tid & 63) == 0) {
                atomicAdd(&scalp[0], a);
                atomicAdd(&scalp[1], bsum);
            }
        }
    }

    auto stage = [&](int buf, int k0) {
#pragma unroll
        for (int j = 0; j < 2; ++j) {          // A: 512 granules
            int i = tid + 256 * j;
            int row = i >> 2, gg = (i & 3) ^ ((i >> 3) & 3);
            g2l16((char*)As[buf] + (size_t)i * 16,
                  A + (size_t)(m0 + row) * 512 + k0 + gg * 8);
        }
        {                                      // B: 256 granules
            int col = tid >> 2, gg = (tid & 3) ^ ((tid >> 3) & 3);
            g2l16((char*)Bs[buf] + (size_t)tid * 16,
                  Bt + (size_t)(n0 + col) * 512 + k0 + gg * 8);
        }
    };

    auto compute = [&](int bi) {
        const char* Ab = (const char*)As[bi];
        const char* Bb = (const char*)Bs[bi];
        short8 af[4], bf[2];
#pragma unroll
        for (int m = 0; m < 4; ++m)
            af[m] = *(const short8*)(Ab + ((wr * 64 + m * 16 + lr) * 4 + prm) * 16);
#pragma unroll
        for (int n = 0; n < 2; ++n)
            bf[n] = *(const short8*)(Bb + ((wc * 32 + n * 16 + lr) * 4 + prm) * 16);
        __builtin_amdgcn_s_setprio(1);
#pragma unroll
        for (int m = 0; m < 4; ++m)
#pragma unroll
            for (int n = 0; n < 2; ++n)
                acc[m][n] = __builtin_amdgcn_mfma_f32_16x16x32_bf16(
                    af[m], bf[n], acc[m][n], 0, 0, 0);
        __builtin_amdgcn_s_setprio(0);
    };

    stage(0, 0);
    stage(1, 32);
    for (int t = 0; t < 14; ++t) {
        stage((t + 2) % 3, (t + 2) * 32);
        GWAITBAR(6);
        compute(t % 3);
        __builtin_amdgcn_s_barrier();
    }
    GWAITBAR(3);
    compute(2);
    GWAITBAR(0);
    compute(0);

    float bs[2] = {bias[n0 + wc * 32 + lr], bias[n0 + wc * 32 + 16 + lr]};
#pragma unroll
    for (int m = 0; m < 4; ++m)
#pragma unroll
        for (int n = 0; n < 2; ++n) {
            int R0  = m0 + wr * 64 + m * 16 + 4 * g;
            int col = n0 + wc * 32 + n * 16 + lr;
            int bbx = R0 >> 10, t0p = R0 & 1023;
            size_t base = (size_t)bbx * C_ * T_ + (size_t)col * T_ + t0p;
            float4 rf;
            rf.x = acc[m][n][0] + bs[n]; rf.y = acc[m][n][1] + bs[n];
            rf.z = acc[m][n][2] + bs[n]; rf.w = acc[m][n][3] + bs[n];
            float4 ffv = *(const float4*)(ffp + base);
            float4 cfv = *(const float4*)&confL[R0 - m0];
            float4 o0v;
            o0v.x = ffv.x + cfv.x * rf.x; o0v.y = ffv.y + cfv.y * rf.y;
            o0v.z = ffv.z + cfv.z * rf.z; o0v.w = ffv.w + cfv.w * rf.w;
            *(float4*)(out1p + base) = rf;
            *(float4*)(out0 + base) = o0v;
        }
}

// ---------------------------------------------------------------------------
// Merged LayerNorms (E and SE). grid 16384: sel = blk>>13. (r11/r14-proven)
__global__ __launch_bounds__(256) void ln2_k(
    const u16* __restrict__ X0, const float* __restrict__ g0,
    const float* __restrict__ b0, u16* __restrict__ O0,
    const u16* __restrict__ X1, const float* __restrict__ g1,
    const float* __restrict__ b1, u16* __restrict__ O1) {
    int sel = blockIdx.x >> 13;
    int row = blockIdx.x & 8191;
    const u16* X = sel ? X1 : X0;
    const float* gw = sel ? g1 : g0;
    const float* bw = sel ? b1 : b0;
    u16* out = sel ? O1 : O0;
    int tid = threadIdx.x;
    const unsigned* xr = (const unsigned*)(X + (size_t)row * D_);
    unsigned u = xr[tid];
    float x0 = bf2f((u16)(u & 0xffff)), x1 = bf2f((u16)(u >> 16));
    float s = x0 + x1, sq = x0 * x0 + x1 * x1;
    __shared__ float rs[4], rq[4];
    for (int o = 32; o; o >>= 1) { s += __shfl_down(s, o); sq += __shfl_down(sq, o); }
    int wid = tid >> 6, lane = tid & 63;
    if (lane == 0) { rs[wid] = s; rq[wid] = sq; }
    __syncthreads();
    if (tid == 0) {
        float ts = 0, tq = 0;
        for (int w = 0; w < 4; ++w) { ts += rs[w]; tq += rq[w]; }
        rs[0] = ts; rq[0] = tq;
    }
    __syncthreads();
    float mean = rs[0] * (1.0f / D_);
    float var  = rq[0] * (1.0f / D_) - mean * mean;
    float r = rsqrtf(var + 1e-5f);
    float2 g2 = *(const float2*)(gw + 2 * tid);
    float2 b2 = *(const float2*)(bw + 2 * tid);
    float y0 = (x0 - mean) * r * g2.x + b2.x;
    float y1 = (x1 - mean) * r * g2.y + b2.y;
    ((unsigned*)(out + (size_t)row * D_))[tid] = pack2(y0, y1);
}

// ---------------------------------------------------------------------------
// head2_k: folded sigma + dustbin heads from E (H1) and PLH (H2), using
// TRANSPOSED weight layouts (dbwT[h][n], wdbfT[h][k]) so every weight load
// is coalesced (32 B lane-stride). One wave per row, 2048 blocks. (r14-proven)
__global__ __launch_bounds__(256) void head2_k(
    const u16* __restrict__ E, const u16* __restrict__ PLH,
    const float* __restrict__ sigw, const float* __restrict__ sigb,
    const float* __restrict__ wsig, const float* __restrict__ dbwT,
    const float* __restrict__ wdbfT, const float* __restrict__ dbb,
    const float* __restrict__ offs,
    float* __restrict__ sigma, float* __restrict__ dbo) {
    int wv = threadIdx.x >> 6, lane = threadIdx.x & 63;
    int row = blockIdx.x * 4 + wv;
    uint4 ue = *((const uint4*)(E + (size_t)row * 512) + lane);
    float Ev[8];
    Ev[0] = bf2f((u16)(ue.x & 0xffff)); Ev[1] = bf2f((u16)(ue.x >> 16));
    Ev[2] = bf2f((u16)(ue.y & 0xffff)); Ev[3] = bf2f((u16)(ue.y >> 16));
    Ev[4] = bf2f((u16)(ue.z & 0xffff)); Ev[5] = bf2f((u16)(ue.z >> 16));
    Ev[6] = bf2f((u16)(ue.w & 0xffff)); Ev[7] = bf2f((u16)(ue.w >> 16));
    uint4 up = *((const uint4*)(PLH + (size_t)row * 512) + lane);
    float plv[8];
    plv[0] = bf2f((u16)(up.x & 0xffff)); plv[1] = bf2f((u16)(up.x >> 16));
    plv[2] = bf2f((u16)(up.y & 0xffff)); plv[3] = bf2f((u16)(up.y >> 16));
    plv[4] = bf2f((u16)(up.z & 0xffff)); plv[5] = bf2f((u16)(up.z >> 16));
    plv[6] = bf2f((u16)(up.w & 0xffff)); plv[7] = bf2f((u16)(up.w >> 16));

    int n0 = lane * 8;
    float4 sw0 = *(const float4*)(sigw + n0);
    float4 sw1 = *(const float4*)(sigw + n0 + 4);
    float4 fw0 = *(const float4*)(wsig + n0);
    float4 fw1 = *(const float4*)(wsig + n0 + 4);
    float swv[8] = {sw0.x, sw0.y, sw0.z, sw0.w, sw1.x, sw1.y, sw1.z, sw1.w};
    float fwv[8] = {fw0.x, fw0.y, fw0.z, fw0.w, fw1.x, fw1.y, fw1.z, fw1.w};
    float sacc = 0;
#pragma unroll
    for (int i = 0; i < 8; ++i) sacc += Ev[i] * swv[i] + plv[i] * fwv[i];

    float d_[8];
#pragma unroll
    for (int h = 0; h < 8; ++h) {
        const float* ar = dbwT + h * 512 + n0;
        const float* br = wdbfT + h * 512 + n0;
        float4 a0v = *(const float4*)ar;
        float4 a1v = *(const float4*)(ar + 4);
        float4 b0v = *(const float4*)br;
        float4 b1v = *(const float4*)(br + 4);
        d_[h] = Ev[0] * a0v.x + Ev[1] * a0v.y + Ev[2] * a0v.z + Ev[3] * a0v.w +
                Ev[4] * a1v.x + Ev[5] * a1v.y + Ev[6] * a1v.z + Ev[7] * a1v.w +
                plv[0] * b0v.x + plv[1] * b0v.y + plv[2] * b0v.z + plv[3] * b0v.w +
                plv[4] * b1v.x + plv[5] * b1v.y + plv[6] * b1v.z + plv[7] * b1v.w;
    }
    for (int o = 1; o < 64; o <<= 1) {
        sacc += __shfl_xor(sacc, o);
#pragma unroll
        for (int h = 0; h < 8; ++h) d_[h] += __shfl_xor(d_[h], o);
    }
    if (lane == 0) {
        float z = sacc + sigb[0] + offs[0];
        sigma[row] = 0.03f + 0.32f / (1.0f + __expf(-z));
        float* dd = dbo + (size_t)row * NH_;
#pragma unroll
        for (int h = 0; h < 8; ++h) dd[h] = d_[h] + dbb[h] + offs[1 + h];
    }
}

// ---------------------------------------------------------------------------
// Staged MFMA flash attention, KVBLK=64, exp2 softmax, 512-thread blocks.
// Issue-then-counted-wait staging (vmcnt(2)); -m_st folded into AbaseM;
// cross-lane max only in rescale branch; l-sum via ones-row MFMA; max3 tree.
// P stays in registers via bit-permuted K staging. 44 KB LDS.
__global__ __launch_bounds__(512) void attn_k(
    const u16* __restrict__ Q, const u16* __restrict__ K,
    const u16* __restrict__ Vt, const float* __restrict__ sig,
    const float* __restrict__ dbl, const float* __restrict__ bev,
    const float* __restrict__ sxy, const void* __restrict__ mask,
    const int* __restrict__ mode, u16* __restrict__ OUT,
    float* __restrict__ dbp) {
    int L = blockIdx.x;
    int W = (L & 7) * 64 + (L >> 3);   // XCD swizzle
    int b = W >> 6, h = (W >> 3) & 7, tblk = W & 7;
    int tid = threadIdx.x, w = tid >> 6, l = tid & 63;
    int lr = l & 15, g = l >> 4;
    int p8 = lr & 7;                   // LDS read granule permutation

    __shared__ u16 Kbuf[2][4096];      // 8 KB each
    __shared__ u16 Vbuf[2][4096];      // 8 KB each
    __shared__ float2 SXY[1024];       // (-2x, -2y)
    __shared__ float  SZ[1024];        // x^2+y^2

    const float2* xp = (const float2*)(sxy + (size_t)b * S_ * 2);
#pragma unroll
    for (int j = 0; j < 2; ++j) {
        int idx = tid + 512 * j;
        float2 v = xp[idx];
        SXY[idx] = make_float2(-2.0f * v.x, -2.0f * v.y);
        SZ[idx] = v.x * v.x + v.y * v.y;
    }

    int trow = b * T_ + tblk * 128 + w * 16 + lr;
    float s_ = sig[trow];
    float bx = bev[(size_t)trow * 2], by = bev[(size_t)trow * 2 + 1];
    float dbv2 = dbl[(size_t)trow * NH_ + h] * INVLN2;
    int md = *mode;
    bool vld = is_valid(mask, md, trow) != 0;
    float grow  = vld ? (-11.5415603271117f / fmaxf(s_ * s_, 1e-6f)) : 0.0f;
    float Abase = vld ? grow * (bx * bx + by * by) : -10000.0f;
    float AbaseM = Abase - dbv2;       // Abase - m_st, maintained across chunks
    float mshift = 0.0f;               // dbv2 - m_st

    const u16* qp = Q + (size_t)trow * 512 + h * 64 + g * 8;
    short8 q0 = *(const short8*)qp;
    short8 q1 = *(const short8*)(qp + 32);
    if (!vld) { q0 = short8{}; q1 = short8{}; }

    short8 ones;
#pragma unroll
    for (int e = 0; e < 8; ++e) ones[e] = (short)0x3F80;   // bf16 1.0

    const u16* Kp = K + (size_t)b * S_ * 512 + h * 64;
    const u16* Vp = Vt + (size_t)(b * 8 + h) * 64 * 1024;

    // staging indices: slot row = tid>>3, permuted granule
    int srow = tid >> 3;                           // 0..63
    int gprm = (tid & 7) ^ (srow & 7);
    // K source row via sigma bit-permutation of the slot row
    int sK = ((srow >> 5) & 1) * 32 + ((srow >> 2) & 3) * 8 +
             ((srow >> 4) & 1) * 4 + (srow & 3);

    auto stageKV = [&](int buf, int s0) {
        g2l16((char*)Kbuf[buf] + (size_t)tid * 16,
              Kp + (size_t)(s0 + sK) * 512 + gprm * 8);
        g2l16((char*)Vbuf[buf] + (size_t)tid * 16,
              Vp + (size_t)srow * 1024 + s0 + gprm * 8);
    };

    f32x4 o0 = {}, o1 = {}, o2 = {}, o3 = {};
    f32x4 o4 = {1.0f, 1.0f, 1.0f, 1.0f};   // l-accumulator (dustbin term = 1)

    stageKV(0, 0);
    int cur = 0;
    for (int c = 0; c < 16; ++c) {
        int s0c = c * 64;
        if (c < 15) {
            stageKV(cur ^ 1, s0c + 64);
            GWAITBAR(2);               // chunk c landed; next chunk in flight
        } else {
            GWAITBAR(0);
        }

        const char* Kc = (const char*)Kbuf[cur];
        const char* Vc = (const char*)Vbuf[cur];

        f32x4 p[4];
        f32x4 z4 = {};
        __builtin_amdgcn_s_setprio(1);
#pragma unroll
        for (int sub = 0; sub < 4; ++sub) {
            int krow = sub * 16 + lr;
            short8 kf0 = *(const short8*)(Kc + (krow * 8 + (g ^ p8)) * 16);
            short8 kf1 = *(const short8*)(Kc + (krow * 8 + ((4 + g) ^ p8)) * 16);
            p[sub] = __builtin_amdgcn_mfma_f32_16x16x32_bf16(kf0, q0, z4, 0, 0, 0);
            p[sub] = __builtin_amdgcn_mfma_f32_16x16x32_bf16(kf1, q1, p[sub], 0, 0, 0);
        }
        __builtin_amdgcn_s_setprio(0);

        // logits, already max-shifted: lg = raw - m_st
        float lg[16];
#pragma unroll
        for (int sub = 0; sub < 4; ++sub) {
            int sl = s0c + ((sub & 2) << 4) + 8 * g + ((sub & 1) << 2);
            float4 xy01 = *(const float4*)&SXY[sl];
            float4 xy23 = *(const float4*)&SXY[sl + 2];
            float4 zz   = *(const float4*)&SZ[sl];
            float X[4] = {xy01.x, xy01.z, xy23.x, xy23.z};
            float Y[4] = {xy01.y, xy01.w, xy23.y, xy23.w};
            float Z[4] = {zz.x, zz.y, zz.z, zz.w};
#pragma unroll
            for (int i2 = 0; i2 < 4; ++i2) {
                float wg = fmaf(bx, X[i2], fmaf(by, Y[i2], Z[i2]));
                lg[sub * 4 + i2] = fmaf(grow, wg, p[sub][i2] + AbaseM);
            }
        }
        // local max via max3 tree
        float c0 = max3f(lg[0], lg[1], lg[2]);
        float c1 = max3f(lg[3], lg[4], lg[5]);
        float c2 = max3f(lg[6], lg[7], lg[8]);
        float c3 = max3f(lg[9], lg[10], lg[11]);
        float c4 = max3f(lg[12], lg[13], lg[14]);
        float cl = fmaxf(max3f(c0, c1, c2), max3f(c3, c4, lg[15]));

        if (!__all(cl <= 11.5f)) {            // rare: true max exceeds m_st+THR
            cl = fmaxf(cl, __shfl_xor(cl, 16));
            cl = fmaxf(cl, __shfl_xor(cl, 32));
            float dm = fmaxf(cl, 0.0f);       // m_new - m_st
            float scl = fexp2(-dm);
            o0 *= scl; o1 *= scl; o2 *= scl; o3 *= scl; o4 *= scl;
            AbaseM -= dm;
            mshift -= dm;
#pragma unroll
            for (int r = 0; r < 16; ++r) lg[r] -= dm;
        }
        float pe[16];
#pragma unroll
        for (int r = 0; r < 16; ++r) pe[r] = fexp2(lg[r]);

        union { uint4 u; short8 s8; } pf0, pf1;
        pf0.u.x = pack2(pe[0], pe[1]);  pf0.u.y = pack2(pe[2], pe[3]);
        pf0.u.z = pack2(pe[4], pe[5]);  pf0.u.w = pack2(pe[6], pe[7]);
        pf1.u.x = pack2(pe[8], pe[9]);  pf1.u.y = pack2(pe[10], pe[11]);
        pf1.u.z = pack2(pe[12], pe[13]); pf1.u.w = pack2(pe[14], pe[15]);

        __builtin_amdgcn_s_setprio(1);
        short8 vf;
#pragma unroll
        for (int dt = 0; dt < 4; ++dt) {
            int vrow = dt * 16 + lr;
            f32x4* oo = (dt == 0) ? &o0 : (dt == 1) ? &o1 : (dt == 2) ? &o2 : &o3;
            vf = *(const short8*)(Vc + (vrow * 8 + (g ^ p8)) * 16);
            *oo = __builtin_amdgcn_mfma_f32_16x16x32_bf16(vf, pf0.s8, *oo, 0, 0, 0);
            vf = *(const short8*)(Vc + (vrow * 8 + ((4 + g) ^ p8)) * 16);
            *oo = __builtin_amdgcn_mfma_f32_16x16x32_bf16(vf, pf1.s8, *oo, 0, 0, 0);
        }
        // l-sum on the matrix pipe: ones-row x P
        o4 = __builtin_amdgcn_mfma_f32_16x16x32_bf16(ones, pf0.s8, o4, 0, 0, 0);
        o4 = __builtin_amdgcn_mfma_f32_16x16x32_bf16(ones, pf1.s8, o4, 0, 0, 0);
        __builtin_amdgcn_s_setprio(0);

        __builtin_amdgcn_s_barrier();   // all reads of buf cur done before reuse
        cur ^= 1;
    }

    float inv = 1.0f / o4[0];
    u16* ob = OUT + (size_t)trow * 512 + h * 64;
    {
        uint2 pk;
        pk.x = pack2(o0[0] * inv, o0[1] * inv); pk.y = pack2(o0[2] * inv, o0[3] * inv);
        *(uint2*)(ob + 0 * 16 + 4 * g) = pk;
        pk.x = pack2(o1[0] * inv, o1[1] * inv); pk.y = pack2(o1[2] * inv, o1[3] * inv);
        *(uint2*)(ob + 1 * 16 + 4 * g) = pk;
        pk.x = pack2(o2[0] * inv, o2[1] * inv); pk.y = pack2(o2[2] * inv, o2[3] * inv);
        *(uint2*)(ob + 2 * 16 + 4 * g) = pk;
        pk.x = pack2(o3[0] * inv, o3[1] * inv); pk.y = pack2(o3[2] * inv, o3[3] * inv);
        *(uint2*)(ob + 3 * 16 + 4 * g) = pk;
    }
    if (g == 0) dbp[(size_t)trow * NH_ + h] = fexp2(mshift) * inv;
}

__global__ void loss_k(const float* __restrict__ scal, float* __restrict__ out) {
    out[0] = scal[0] / fmaxf(scal[1], 1.0f) * 0.05f;
}

// ---------------------------------------------------------------------------
extern "C" void kernel_launch(void* const* d_in, const int* in_sizes, int n_in,
                              void* d_out, int out_size, void* d_ws, size_t ws_size,
                              hipStream_t stream) {
    const float* front_feat = (const float*)d_in[0];
    const float* sat_tokens = (const float*)d_in[1];
    const float* sat_xy     = (const float*)d_in[2];
    const float* bev_xy     = (const float*)d_in[3];
    const void*  mask       = d_in[4];
    const float* plucker    = (const float*)d_in[5];
    const float* fa_w = (const float*)d_in[6];
    const float* fa_b = (const float*)d_in[7];
    const float* fa_g = (const float*)d_in[8];
    const float* fa_lb = (const float*)d_in[9];
    const float* sa_w = (const float*)d_in[10];
    const float* sa_b = (const float*)d_in[11];
    const float* sa_g = (const float*)d_in[12];
    const float* sa_lb = (const float*)d_in[13];
    const float* q_w = (const float*)d_in[14];
    const float* q_b = (const float*)d_in[15];
    const float* k_w = (const float*)d_in[16];
    const float* k_b = (const float*)d_in[17];
    const float* v_w = (const float*)d_in[18];
    const float* v_b = (const float*)d_in[19];
    const float* pl_w1 = (const float*)d_in[20];
    const float* pl_b1 = (const float*)d_in[21];
    const float* pl_w2 = (const float*)d_in[22];
    const float* pl_b2 = (const float*)d_in[23];
    const float* sig_w = (const float*)d_in[24];
    const float* sig_b = (const float*)d_in[25];
    const float* db_w = (const float*)d_in[26];
    const float* db_b = (const float*)d_in[27];
    const float* out_w = (const float*)d_in[28];
    const float* out_b = (const float*)d_in[29];

    char* w8 = (char*)d_ws;
    u16* H0 = (u16*)(w8);                        // 8 MB bf16 slots
    u16* H1 = (u16*)(w8 + 8388608ull * 1);
    u16* H2 = (u16*)(w8 + 8388608ull * 2);
    u16* H3 = (u16*)(w8 + 8388608ull * 3);
    u16* H4 = (u16*)(w8 + 8388608ull * 4);
    u16* H5 = (u16*)(w8 + 8388608ull * 5);
    u16* H6 = (u16*)(w8 + 8388608ull * 6);
    u16* WT = (u16*)(w8 + 8388608ull * 7);       // 6 x 0.5 MB
    char* sm = w8 + 8388608ull * 7 + 3670016ull;
    float* w_sigma = (float*)sm;
    float* w_db    = w_sigma + BT_;
    float* w_dbp   = w_db + (size_t)BT_ * NH_;
    float* w_scal  = w_dbp + (size_t)BT_ * NH_;
    int*   w_mode  = (int*)(w_scal + 2);
    float* w_wsig  = w_scal + 4;                 // 512
    float* w_wdbfT = w_wsig + 512;               // 4096
    float* w_offs  = w_wdbfT + 4096;             // 9 (pad to 16)
    float* w_dbwT  = w_offs + 16;                // 4096

    u16* Wfa = WT;                 u16* Wq  = WT + 262144ull * 1;
    u16* Wsa = WT + 262144ull * 2; u16* Wk  = WT + 262144ull * 3;
    u16* Wv  = WT + 262144ull * 4; u16* Wo  = WT + 262144ull * 5;

    float* out0 = (float*)d_out;
    float* out1 = out0 + (size_t)B_ * C_ * T_;
    float* outc = out1 + (size_t)B_ * C_ * T_;
    float* outl = outc + (size_t)B_ * T_;

    dim3 blk(256);

    // 1. prep: mode + 6 weight transposes + front transpose (H0) + sat (H5)
    //    + plucker hidden (H2) + parallelized head weight folds
    prep_k<<<dim3(10243), blk, 0, stream>>>(
        front_feat, sat_tokens, plucker,
        fa_w, q_w, sa_w, k_w, v_w, out_w, WT,
        H0, H5, pl_w1, pl_b1, H2,
        (const unsigned*)mask, w_mode, w_scal,
        pl_w2, sig_w, db_w, pl_b2, w_wsig, w_wdbfT, w_offs, w_dbwT);
    // 2. E_pre (H0@Wfa -> H6) and SAT_pre (H5@Wsa -> H4), 512 blocks
    gmm_k<<<dim3(512), blk, 0, stream>>>(
        H0, H5, nullptr,
        Wfa, Wsa, nullptr,
        fa_b, sa_b, nullptr,
        H6, H4, nullptr,
        0, 0, 0);
    // 3. LN(E_pre)->H1, LN(SAT_pre)->H3
    ln2_k<<<dim3(16384), blk, 0, stream>>>(H6, fa_g, fa_lb, H1,
                                           H4, sa_g, sa_lb, H3);
    // 4. sigma/dustbin heads from E (H1) + PLH (H2), folded+coalesced
    head2_k<<<dim3(2048), blk, 0, stream>>>(
        H1, H2, sig_w, sig_b, w_wsig, w_dbwT, w_wdbfT, db_b, w_offs,
        w_sigma, w_db);
    // 5. Q (H1->H5, scale), K (H3->H0), Vt (H3->H4 scatter), 768 blocks
    gmm_k<<<dim3(768), blk, 0, stream>>>(
        H1, H3, H3,
        Wq, Wk, Wv,
        q_b, k_b, v_b,
        H5, H0, H4,
        1, 0, 3);
    // 6. attention: Q=H5, K=H0, Vt=H4 -> OUT=H2
    attn_k<<<dim3(512), dim3(512), 0, stream>>>(
        H5, H0, H4, w_sigma, w_db, bev_xy, sat_xy, mask, w_mode, H2, w_dbp);
    // 7. RF = H2 @ Wo (128x64 tiles, 512 blocks), fused transposed epilogue
    //    + in-kernel confidence/loss
    rf64_k<<<dim3(512), blk, 0, stream>>>(
        H2, Wo, out_b, out0, front_feat, out1,
        w_dbp, mask, w_mode, outc, w_scal);
    // 8. loss scalar
    loss_k<<<1, 1, 0, stream>>>(w_scal, outl);
}